// Round 10
// baseline (2289.714 us; speedup 1.0000x reference)
//
#include <hip/hip_runtime.h>
#include <cstdint>

#define EPS 1e-5f
typedef float f32x4 __attribute__((ext_vector_type(4)));
typedef short bf8 __attribute__((ext_vector_type(8)));   // 8 bf16 vals (4 VGPRs)
typedef unsigned short u16;
typedef unsigned short u16x8 __attribute__((ext_vector_type(8)));
typedef unsigned int uint4v __attribute__((ext_vector_type(4)));

__device__ __forceinline__ u16 f2b(float f){
  unsigned x = __float_as_uint(f);
  unsigned r = x + 0x7FFFu + ((x>>16)&1u);   // round-to-nearest-even
  return (u16)(r>>16);
}
__device__ __forceinline__ float b2f(u16 h){ return __uint_as_float(((unsigned)h)<<16); }
// pack two f32 -> one dword of 2 bf16 (a in low half); round-half-up
__device__ __forceinline__ unsigned pk2(float a, float b){
  unsigned ua = __float_as_uint(a) + 0x8000u;
  unsigned ub = __float_as_uint(b) + 0x8000u;
  return __builtin_amdgcn_perm(ub, ua, 0x07060302u);
}

#define GLL(gp, lp) __builtin_amdgcn_global_load_lds((__attribute__((address_space(1))) const void*)(gp), (__attribute__((address_space(3))) void*)(lp), 16, 0, 0)

// ---------------------------------------------------------------- K0a: expm + M1/M2 tables
// R14 = R13 with the dcm/ft overlap FIXED (R13 placed dcm inside the doubled ft table;
// k_prep's O2 writes clobbered it). F(v)_p = Sum_q v_q*W2[q][p] - cmn[p]*(1^T v) is LINEAR
// -> M1[q][p] = W2[q][p]-cmn[p], M2 = M1*M1 (exact fp32). Scan advances 2 tokens/step by
// applying M1 and M2 to the same packed state in PARALLEL MFMAs. Tables: O1/O2 =
// offdiag(M1/M2) bf16 (rank-one folded; entries small, contraction damps — R7's argument);
// D1/D2 = diag fp32. M1/M2 also written fp32 for k_fc.
__global__ __launch_bounds__(1024) void k_prep(const float* __restrict__ A, const float* __restrict__ dtp,
    const float* __restrict__ stg, const float* __restrict__ stb,
    float* __restrict__ abeta, u16* __restrict__ ft, float* __restrict__ dcm,
    float* __restrict__ m1g, float* __restrict__ m2g)
{
  __shared__ float M[4096], Ta[4096], Tb[4096], P[4096];
  __shared__ float cmn[64];
  int tid = threadIdx.x;
  float dt = dtp[0];
  for (int e=tid; e<4096; e+=1024){
    float v = dt * A[e];
    int i = e>>6, j = e&63;
    M[e] = v;
    P[e] = v + (i==j ? 1.0f : 0.0f);
    Ta[e] = v;
  }
  __syncthreads();
  float* src = Ta; float* dst = Tb;
  for (int k=2;k<=14;k++){
    float inv = 1.0f/(float)k;
    int i = tid>>4, j0 = (tid&15)*4;
    float a0=0,a1=0,a2=0,a3=0;
    for (int m2=0;m2<64;m2++){
      float f = src[i*64+m2];
      const float* Mr = &M[m2*64+j0];
      a0 += f*Mr[0]; a1 += f*Mr[1]; a2 += f*Mr[2]; a3 += f*Mr[3];
    }
    a0*=inv; a1*=inv; a2*=inv; a3*=inv;
    int base=i*64+j0;
    dst[base+0]=a0; dst[base+1]=a1; dst[base+2]=a2; dst[base+3]=a3;
    P[base+0]+=a0; P[base+1]+=a1; P[base+2]+=a2; P[base+3]+=a3;
    __syncthreads();
    float* tmp=src; src=dst; dst=tmp;
  }
  if (tid<64){
    float c0=0, ab=0; int p = tid;
    for (int q2=0;q2<64;q2++){ float ap = P[q2*64+p]; c0 += stg[q2]*ap; ab += stb[q2]*ap; }
    cmn[p] = c0*(1.0f/64.0f);
    abeta[p] = ab;
  }
  __syncthreads();
  // M1 into Ta
  for (int e=tid; e<4096; e+=1024){
    int q2=e>>6, p=e&63;
    Ta[e] = stg[q2]*P[e] - cmn[p];
  }
  __syncthreads();
  // M2 = M1*M1 into Tb
  {
    int i = tid>>4, j0 = (tid&15)*4;
    float a0=0,a1=0,a2=0,a3=0;
    for (int m2=0;m2<64;m2++){
      float f = Ta[i*64+m2];
      const float* Mr = &Ta[m2*64+j0];
      a0 += f*Mr[0]; a1 += f*Mr[1]; a2 += f*Mr[2]; a3 += f*Mr[3];
    }
    int base=i*64+j0;
    Tb[base+0]=a0; Tb[base+1]=a1; Tb[base+2]=a2; Tb[base+3]=a3;
  }
  __syncthreads();
  // export fp32 M1/M2 for k_fc; diag tables (dcm now OUTSIDE the ft region)
  for (int e=tid; e<4096; e+=1024){ m1g[e]=Ta[e]; m2g[e]=Tb[e]; }
  if (tid<64){
    dcm[tid]    = Ta[tid*64+tid];   // D1
    dcm[64+tid] = Tb[tid*64+tid];   // D2
  }
  // fragment tables: A-operand map (matrix stored [q][p]); diag zeroed; O1 then O2.
  for (int ii=0; ii<4; ii++){
    int e = tid*4+ii;
    int j = e&7, l = (e>>3)&63, kt=(e>>9)&1, mt=e>>10;
    int q2 = 16*(2*kt + (j>>2)) + 4*(l>>4) + (j&3);
    int p = 16*mt + (l&15);
    ft[e]      = f2b(q2==p ? 0.0f : Ta[q2*64+p]);
    ft[e+4096] = f2b(q2==p ? 0.0f : Tb[q2*64+p]);
  }
}

// ---------------------------------------------------------------- K0b: weights -> bf16
__global__ __launch_bounds__(256) void k_wcvt(const float* __restrict__ gw, const float* __restrict__ bw,
   const float* __restrict__ cw, const float* __restrict__ dw,
   u16* __restrict__ ogw, u16* __restrict__ obw, u16* __restrict__ ocw, u16* __restrict__ odw)
{
  int n = blockIdx.x*256 + threadIdx.x;
  if (n < 2097152) ogw[n] = f2b(gw[n]);
  else if (n < 2162688) obw[n-2097152] = f2b(bw[n-2097152]);
  else if (n < 2228224) ocw[n-2162688] = f2b(cw[n-2162688]);
  else odw[n-2228224] = f2b(dw[n-2228224]);
}

// ---------------------------------------------------------------- K1: layernorm + depthwise conv + residual -> bf16
__global__ __launch_bounds__(256) void k_lnconv(const float* __restrict__ x, const float* __restrict__ gin,
  const float* __restrict__ bin, const float* __restrict__ cwt, const float* __restrict__ cb, u16* __restrict__ xn)
{
  __shared__ float red[10][8];
  int tid = threadIdx.x; int w = tid>>6; int lane = tid&63;
  int r0 = blockIdx.x*8;
  int bt = r0>>12, t0 = r0&4095;
  int c4 = tid*4;
  f32x4 g4 = *(const f32x4*)(gin + c4);
  f32x4 b4 = *(const f32x4*)(bin + c4);
  f32x4 vals[10];
  for (int lr=0; lr<10; lr++){
    int t = t0 - 1 + lr;
    f32x4 xv = {0,0,0,0};
    bool ok = (t>=0 && t<4096);
    if (ok) xv = *(const f32x4*)(x + (size_t)(bt*4096+t)*1024 + c4);
    float s = xv.x+xv.y+xv.z+xv.w;
    float q = xv.x*xv.x+xv.y*xv.y+xv.z*xv.z+xv.w*xv.w;
    for (int m2=1;m2<=32;m2<<=1){ s += __shfl_xor(s,m2,64); q += __shfl_xor(q,m2,64); }
    if (lane==0){ red[lr][w]=s; red[lr][4+w]=q; }
    __syncthreads();
    s = red[lr][0]+red[lr][1]+red[lr][2]+red[lr][3];
    q = red[lr][4]+red[lr][5]+red[lr][6]+red[lr][7];
    float mu = s*(1.f/1024.f);
    float var = q*(1.f/1024.f) - mu*mu;
    float rr = rsqrtf(var + EPS);
    f32x4 o = {0,0,0,0};
    if (ok){
      o.x=(xv.x-mu)*rr*g4.x+b4.x; o.y=(xv.y-mu)*rr*g4.y+b4.y;
      o.z=(xv.z-mu)*rr*g4.z+b4.z; o.w=(xv.w-mu)*rr*g4.w+b4.w;
    }
    vals[lr]=o;
  }
  float w0[4], w1[4], w2[4], cbv[4];
  for (int ii=0;ii<4;ii++){ int c = c4+ii; w0[ii]=cwt[c*3+0]; w1[ii]=cwt[c*3+1]; w2[ii]=cwt[c*3+2]; cbv[ii]=cb[c]; }
  for (int lr=1; lr<=8; lr++){
    int t = t0 + lr - 1;
    f32x4 o;
    o.x = vals[lr].x + w0[0]*vals[lr-1].x + w1[0]*vals[lr].x + w2[0]*vals[lr+1].x + cbv[0];
    o.y = vals[lr].y + w0[1]*vals[lr-1].y + w1[1]*vals[lr].y + w2[1]*vals[lr+1].y + cbv[1];
    o.z = vals[lr].z + w0[2]*vals[lr-1].z + w1[2]*vals[lr].z + w2[2]*vals[lr+1].z + cbv[2];
    o.w = vals[lr].w + w0[3]*vals[lr-1].w + w1[3]*vals[lr].w + w2[3]*vals[lr+1].w + cbv[3];
    size_t off = (size_t)(bt*4096+t)*1024 + c4;
    unsigned lo2 = (unsigned)f2b(o.x) | ((unsigned)f2b(o.y)<<16);
    unsigned hi2 = (unsigned)f2b(o.z) | ((unsigned)f2b(o.w)<<16);
    uint2 pk; pk.x=lo2; pk.y=hi2;
    *(uint2*)(xn + off) = pk;
  }
}

// ---------------------------------------------------------------- K2: gate GEMM + sigmoid + xg (R6 epilogue)
__global__ __launch_bounds__(256) void k_gate(const u16* __restrict__ xn, const u16* __restrict__ gw,
    const float* __restrict__ gb, u16* __restrict__ gate_o, u16* __restrict__ xg_o)
{
  __shared__ char smem[33792];
  u16* As = (u16*)smem;
  u16* Bs = (u16*)(smem + 8192);
  float* st = (float*)smem;
  int tid=threadIdx.x, w=tid>>6, l=tid&63;
  int flat = blockIdx.x + (int)gridDim.x*blockIdx.y;
  int logical = (flat&7)*256 + (flat>>3);
  int n0 = (logical&15)*128, m0 = (logical>>4)*128;
  int wr = w>>1, wc = w&1;
  f32x4 acc[4][4] = {};
  for (int kk=0; kk<32; kk++){
    int k0 = kk*32;
    for (int i2=0;i2<2;i2++){
      const char* ga = (const char*)xn + ((size_t)(m0+32*w+16*i2+(l>>2))*1024 + k0)*2 + (l&3)*16;
      GLL(ga, (char*)As + (32*w+16*i2)*64);
      const char* gbp = (const char*)gw + ((size_t)(n0+32*w+16*i2+(l>>2))*1024 + k0)*2 + (l&3)*16;
      GLL(gbp, (char*)Bs + (32*w+16*i2)*64);
    }
    __syncthreads();
    bf8 af[4], bfr[4];
    for (int mt=0;mt<4;mt++) af[mt] = *(const bf8*)(As + (wr*64+mt*16+(l&15))*32 + 8*(l>>4));
    for (int nt=0;nt<4;nt++) bfr[nt] = *(const bf8*)(Bs + (wc*64+nt*16+(l&15))*32 + 8*(l>>4));
    for (int mt=0;mt<4;mt++) for (int nt=0;nt<4;nt++)
      acc[mt][nt] = __builtin_amdgcn_mfma_f32_16x16x32_bf16(af[mt], bfr[nt], acc[mt][nt], 0,0,0);
    __syncthreads();
  }
  bool isxg = (n0 >= 1024);
  int r2 = tid>>2, q = tid&3;
  f32x4 gb4[8];
  for (int j=0;j<8;j++) gb4[j] = *(const f32x4*)(gb + n0 + q*32 + j*4);
  int g = l>>4, c = l&15;
  for (int p=0;p<2;p++){
    __syncthreads();
    if (wr==p){
      for (int mt=0;mt<4;mt++) for (int nt=0;nt<4;nt++)
        for (int r=0;r<4;r++)
          st[(mt*16+4*g+r)*132 + wc*64+nt*16+c] = acc[mt][nt][r];
    }
    __syncthreads();
    int row = m0 + p*64 + r2;
    const float* sp = st + r2*132 + q*32;
    u16 ob[32];
    if (!isxg){
      for (int j=0;j<8;j++){
        f32x4 v = *(const f32x4*)(sp + 4*j);
        v = v + gb4[j];
        ob[4*j+0] = f2b(1.0f/(1.0f+__expf(-v.x)));
        ob[4*j+1] = f2b(1.0f/(1.0f+__expf(-v.y)));
        ob[4*j+2] = f2b(1.0f/(1.0f+__expf(-v.z)));
        ob[4*j+3] = f2b(1.0f/(1.0f+__expf(-v.w)));
      }
    } else {
      const u16* xp = xn + (size_t)row*1024 + (n0-1024) + q*32;
      u16 xb[32];
      for (int j=0;j<4;j++){
        u16x8 t8 = *(const u16x8*)(xp + 8*j);
        for (int e=0;e<8;e++) xb[8*j+e] = t8[e];
      }
      for (int j=0;j<8;j++){
        f32x4 v = *(const f32x4*)(sp + 4*j);
        v = v + gb4[j];
        ob[4*j+0] = f2b(b2f(xb[4*j+0]) * (1.0f/(1.0f+__expf(-v.x))));
        ob[4*j+1] = f2b(b2f(xb[4*j+1]) * (1.0f/(1.0f+__expf(-v.y))));
        ob[4*j+2] = f2b(b2f(xb[4*j+2]) * (1.0f/(1.0f+__expf(-v.z))));
        ob[4*j+3] = f2b(b2f(xb[4*j+3]) * (1.0f/(1.0f+__expf(-v.w))));
      }
    }
    u16* op = isxg ? (xg_o + (size_t)row*1024 + (n0-1024) + q*32)
                   : (gate_o + (size_t)row*1024 + n0 + q*32);
    unsigned od[16];
    for (int i2=0;i2<16;i2++) od[i2] = (unsigned)ob[2*i2] | ((unsigned)ob[2*i2+1]<<16);
    uint4v s0 = {od[0],od[1],od[2],od[3]};
    uint4v s1 = {od[4],od[5],od[6],od[7]};
    uint4v s2 = {od[8],od[9],od[10],od[11]};
    uint4v s3 = {od[12],od[13],od[14],od[15]};
    *(uint4v*)(op+ 0) = s0;
    *(uint4v*)(op+ 8) = s1;
    *(uint4v*)(op+16) = s2;
    *(uint4v*)(op+24) = s3;
  }
}

// ---------------------------------------------------------------- K3: Bm (-> c_ws, scan layout) and Cm (bf16)
__global__ __launch_bounds__(256) void k_bc(const u16* __restrict__ xg, const u16* __restrict__ xn,
   const u16* __restrict__ bw, const u16* __restrict__ cw,
   const float* __restrict__ bb, const float* __restrict__ cbias_, const float* __restrict__ abeta,
   float* __restrict__ c_ws, u16* __restrict__ cm)
{
  __shared__ u16 As[128*32], Bs[64*32];
  int tid=threadIdx.x, w=tid>>6, l=tid&63;
  int id = blockIdx.x; int half = id>>7; int m0 = (id&127)*128;
  const u16* Ap = half ? xn : xg;
  const u16* Bp = half ? cw : bw;
  f32x4 acc[2][4]={};
  for (int kk=0;kk<32;kk++){
    int k0=kk*32;
    for (int i2=0;i2<2;i2++){
      const char* ga=(const char*)Ap + ((size_t)(m0+32*w+16*i2+(l>>2))*1024+k0)*2+(l&3)*16;
      GLL(ga, (char*)As+(32*w+16*i2)*64);
    }
    { const char* gbp=(const char*)Bp + ((size_t)(16*w+(l>>2))*1024+k0)*2+(l&3)*16;
      GLL(gbp, (char*)Bs+(16*w)*64); }
    __syncthreads();
    bf8 af[2], bfr[4];
    for (int mt=0;mt<2;mt++) af[mt]=*(const bf8*)(As+(32*w+16*mt+(l&15))*32+8*(l>>4));
    for (int nt=0;nt<4;nt++) bfr[nt]=*(const bf8*)(Bs+(16*nt+(l&15))*32+8*(l>>4));
    for (int mt=0;mt<2;mt++) for(int nt=0;nt<4;nt++)
      acc[mt][nt]=__builtin_amdgcn_mfma_f32_16x16x32_bf16(af[mt],bfr[nt],acc[mt][nt],0,0,0);
    __syncthreads();
  }
  int g=l>>4, c=l&15;
  if (half==0){
    for (int nt=0;nt<4;nt++){ int n=16*nt+c; float bias=bb[n]; float ab=abeta[n];
      for(int mt=0;mt<2;mt++) for(int r=0;r<4;r++){
        int row=m0+32*w+16*mt+4*g+r; int bt=row>>12, t=row&4095;
        float v=acc[mt][nt][r]+bias + (t>0?ab:0.0f);
        c_ws[(size_t)t*256 + bt*64 + n] = v;
      }
    }
  } else {
    for (int nt=0;nt<4;nt++){ int n=16*nt+c; float bias=cbias_[n];
      for(int mt=0;mt<2;mt++) for(int r=0;r<4;r++){
        int row=m0+32*w+16*mt+4*g+r;
        cm[(size_t)row*64+n]=f2b(acc[mt][nt][r]+bias);
      }
    }
  }
}

// ---------------------------------------------------------------- K3b: Fc = M1^T c, FFc = M2^T c, bf16 chunk layout
// layout: record t (512B): chunk (b*4+g)*32B holds comps {16mt+4g+rr} as bf16 at u16 idx mt*4+rr.
__global__ __launch_bounds__(256) void k_fc(const float* __restrict__ c_ws,
  const float* __restrict__ m1g, const float* __restrict__ m2g,
  u16* __restrict__ fc, u16* __restrict__ ffc)
{
  __shared__ float M1s[4096], M2s[4096], Cs[4096];
  int tid=threadIdx.x; int t0=blockIdx.x*16;
  for (int e=tid; e<4096; e+=256){
    M1s[e]=m1g[e]; M2s[e]=m2g[e];
    int row=e>>6, q=e&63;
    Cs[e]=c_ws[(size_t)(t0+(row>>2))*256 + (row&3)*64 + q];
  }
  __syncthreads();
  int row=tid>>2, pq=tid&3;
  const float* cr=&Cs[row*64];
  float f1[16], f2[16];
  #pragma unroll
  for (int k2=0;k2<16;k2++){ f1[k2]=0.f; f2[k2]=0.f; }
  for (int q=0;q<64;q++){
    float cq=cr[q];
    const float* r1=&M1s[q*64+pq*16];
    const float* r2=&M2s[q*64+pq*16];
    #pragma unroll
    for (int k2=0;k2<16;k2++){ f1[k2]+=cq*r1[k2]; f2[k2]+=cq*r2[k2]; }
  }
  int t=t0+(row>>2), b=row&3;
  #pragma unroll
  for (int gp=0;gp<4;gp++){
    uint2 o1, o2;
    o1.x = pk2(f1[gp*4+0], f1[gp*4+1]); o1.y = pk2(f1[gp*4+2], f1[gp*4+3]);
    o2.x = pk2(f2[gp*4+0], f2[gp*4+1]); o2.y = pk2(f2[gp*4+2], f2[gp*4+3]);
    size_t off = (size_t)t*256 + (size_t)((b*4+gp)*16 + pq*4);
    *(uint2*)(fc+off) = o1;
    *(uint2*)(ffc+off) = o2;
  }
}

// ---------------------------------------------------------------- K4: sequential scan — 2 tokens per step.
// State: G = F(z) fp32 + packed Ĝ + rr. Per iteration (tokens t+1, t+2):
//   MFMA (parallel): H = O1⊗Ĝ, K = O2⊗Ĝ  (+D1∘G / +D2∘G fp32)
//   z_{t+1} = rr·G + c_{t+1};  rr1 = LNrr(z_{t+1})
//   G_{t+1} = rr·(M1^T G) + Fc_{t+1}; z_{t+2} = rr1·G_{t+1} + c_{t+2}; rr2 = LNrr(z_{t+2})
//   G_{t+2} = rr1·rr·(M2^T G) + rr1·FFc_{t+1} + Fc_{t+2}
// One wait→MFMA→pack cycle per 2 tokens (R5-R11 established an ~800cy/cycle floor
// invariant to content — amortize it). z stored bf16 (k_y adapted).
__global__ __launch_bounds__(64,1) void k_scan(const float* __restrict__ c_ws, const u16* __restrict__ ft,
  const float* __restrict__ dcm, const u16* __restrict__ fc_ws, const u16* __restrict__ ffc_ws,
  u16* __restrict__ zb16)
{
  int l=threadIdx.x, g=l>>4, b=l&3;
  const bf8* ftv=(const bf8*)ft;
  bf8 O1f[4][2], O2f[4][2];
  for(int mt=0;mt<4;mt++)for(int kt=0;kt<2;kt++){
    O1f[mt][kt]=ftv[(mt*2+kt)*64+l];
    O2f[mt][kt]=ftv[(8+mt*2+kt)*64+l];
  }
  f32x4 D1r[4], D2r[4];
  for(int mt=0;mt<4;mt++){
    D1r[mt]=*(const f32x4*)(dcm+16*mt+4*g);
    D2r[mt]=*(const f32x4*)(dcm+64+16*mt+4*g);
  }
  const f32x4 zed={0.f,0.f,0.f,0.f};
  unsigned cbase=(unsigned)((b*64+4*g)*4);
  unsigned fbase=(unsigned)((b*4+g)*32);
  unsigned long long cbse=(unsigned long long)(uintptr_t)c_ws;
  unsigned long long fbse=(unsigned long long)(uintptr_t)fc_ws;
  unsigned long long hbse=(unsigned long long)(uintptr_t)ffc_ws;
  unsigned long long zb  =(unsigned long long)(uintptr_t)zb16;
  bool stl = ((l&15)<4);

#define MF(Aop,Bop,Cin) __builtin_amdgcn_mfma_f32_16x16x32_bf16(Aop,Bop,Cin,0,0,0)
#define UNPK(D, U, i0, i1) { D.x=__uint_as_float((U)[i0]<<16); D.y=__uint_as_float((U)[i0]&0xffff0000u); \
                             D.z=__uint_as_float((U)[i1]<<16); D.w=__uint_as_float((U)[i1]&0xffff0000u); }
#define PACKZ(Z0,Z1,Z2,Z3, P0,P1) { \
  P0.x=pk2(Z0.x,Z0.y); P0.y=pk2(Z0.z,Z0.w); P0.z=pk2(Z1.x,Z1.y); P0.w=pk2(Z1.z,Z1.w); \
  P1.x=pk2(Z2.x,Z2.y); P1.y=pk2(Z2.z,Z2.w); P1.z=pk2(Z3.x,Z3.y); P1.w=pk2(Z3.z,Z3.w); }
#define REDUCE_RR(Z0,Z1,Z2,Z3, RR) { \
  f32x4 s4=((Z0)+(Z1))+((Z2)+(Z3)); float s=(s4.x+s4.y)+(s4.z+s4.w); \
  f32x4 qa=(Z0)*(Z0); qa=(Z1)*(Z1)+qa; f32x4 qb=(Z2)*(Z2); qb=(Z3)*(Z3)+qb; f32x4 q4=qa+qb; \
  float q=(q4.x+q4.y)+(q4.z+q4.w); \
  float sB=s,qB=q; asm("v_permlane16_swap_b32 %0, %1":"+v"(s),"+v"(sB)); \
  asm("v_permlane16_swap_b32 %0, %1":"+v"(q),"+v"(qB)); s+=sB;q+=qB; \
  float sC=s,qC=q; asm("v_permlane32_swap_b32 %0, %1":"+v"(s),"+v"(sC)); \
  asm("v_permlane32_swap_b32 %0, %1":"+v"(q),"+v"(qC)); s+=sC;q+=qC; \
  float mu=s*(1.f/64.f); float var=q*(1.f/64.f)-mu*mu; RR=rsqrtf(var+EPS); }
#define LD_C(R0,R1,R2,R3, OFF) asm volatile( \
  "global_load_dwordx4 %0, %4, %5 offset:0\n\t" \
  "global_load_dwordx4 %1, %4, %5 offset:64\n\t" \
  "global_load_dwordx4 %2, %4, %5 offset:128\n\t" \
  "global_load_dwordx4 %3, %4, %5 offset:192" \
  : "=&v"(R0),"=&v"(R1),"=&v"(R2),"=&v"(R3) : "v"(OFF), "s"(cbse) : "memory")
#define LD_C2(R0,R1,R2,R3, OFF) asm volatile( \
  "global_load_dwordx4 %0, %4, %5 offset:1024\n\t" \
  "global_load_dwordx4 %1, %4, %5 offset:1088\n\t" \
  "global_load_dwordx4 %2, %4, %5 offset:1152\n\t" \
  "global_load_dwordx4 %3, %4, %5 offset:1216" \
  : "=&v"(R0),"=&v"(R1),"=&v"(R2),"=&v"(R3) : "v"(OFF), "s"(cbse) : "memory")
#define LD_F(Ra,Rb, OFF, BASE) asm volatile( \
  "global_load_dwordx4 %0, %2, %3 offset:0\n\t" \
  "global_load_dwordx4 %1, %2, %3 offset:16" \
  : "=&v"(Ra),"=&v"(Rb) : "v"(OFF), "s"(BASE) : "memory")
#define LD_F2(Ra,Rb, OFF, BASE) asm volatile( \
  "global_load_dwordx4 %0, %2, %3 offset:512\n\t" \
  "global_load_dwordx4 %1, %2, %3 offset:528" \
  : "=&v"(Ra),"=&v"(Rb) : "v"(OFF), "s"(BASE) : "memory")
#define ST_Z(P0,P1, VO) if(stl){ asm volatile( \
  "global_store_dwordx4 %0, %1, %3\n\t" \
  "global_store_dwordx4 %0, %2, %3 offset:16" \
  :: "v"(VO), "v"(P0), "v"(P1), "s"(zb) : "memory"); }

  // ---- prologue: z0 = c0; G0 = Fc_0; rr0; pack; store ẑ0
  f32x4 z00,z01,z02,z03;
  { const float* zp = c_ws + b*64 + 4*g;
    z00=*(const f32x4*)(zp); z01=*(const f32x4*)(zp+16); z02=*(const f32x4*)(zp+32); z03=*(const f32x4*)(zp+48); }
  f32x4 Gs0,Gs1,Gs2,Gs3;
  { const uint4v* fp=(const uint4v*)((const char*)fc_ws + fbase);
    uint4v ga=fp[0], gb2=fp[1];
    UNPK(Gs0, ga,0,1); UNPK(Gs1, ga,2,3); UNPK(Gs2, gb2,0,1); UNPK(Gs3, gb2,2,3); }
  float rr; REDUCE_RR(z00,z01,z02,z03, rr);
  bf8 zf0, zf1;
  { uint4v p0,p1; PACKZ(Gs0,Gs1,Gs2,Gs3,p0,p1);
    union{uint4v u; bf8 h;}cv; cv.u=p0; zf0=cv.h; cv.u=p1; zf1=cv.h; }
  unsigned voff = fbase;                 // z record 0 chunk base
  { uint4v q0,q1; PACKZ(z00,z01,z02,z03,q0,q1); ST_Z(q0,q1, voff); }
  voff += 512u;
  // ---- double-buffered prefetch (A: iter 0 = tokens 1,2; B: iter 1 = tokens 3,4)
  f32x4 cA10,cA11,cA12,cA13, cA20,cA21,cA22,cA23;
  f32x4 cB10,cB11,cB12,cB13, cB20,cB21,cB22,cB23;
  uint4v fA1a,fA1b, fA2a,fA2b, hA1a,hA1b;
  uint4v fB1a,fB1b, fB2a,fB2b, hB1a,hB1b;
  unsigned cOfA = 1024u + cbase,  fOfA = 512u + fbase;
  unsigned cOfB = 3072u + cbase,  fOfB = 1536u + fbase;
  LD_C (cA10,cA11,cA12,cA13, cOfA); LD_C2(cA20,cA21,cA22,cA23, cOfA);
  LD_F (fA1a,fA1b, fOfA, fbse); LD_F2(fA2a,fA2b, fOfA, fbse); LD_F(hA1a,hA1b, fOfA, hbse);
  cOfA += 4096u; fOfA += 2048u;
  LD_C (cB10,cB11,cB12,cB13, cOfB); LD_C2(cB20,cB21,cB22,cB23, cOfB);
  LD_F (fB1a,fB1b, fOfB, fbse); LD_F2(fB2a,fB2b, fOfB, fbse); LD_F(hB1a,hB1b, fOfB, hbse);
  cOfB += 4096u; fOfB += 2048u;
  asm volatile("s_waitcnt vmcnt(0)" ::: "memory");

// per-iter vm ops: 4 stores + 14 loads = 18. Buffer consumed at iter i reloaded at iter i-2;
// ops issued after its loads = iter i-1's 18 -> wait vmcnt(18) guarantees retirement.
#define ITER(C10,C11,C12,C13,C20,C21,C22,C23, F1a,F1b,F2a,F2b, H1a,H1b, COF, FOF) do{ \
  asm volatile("s_waitcnt vmcnt(18)" : "+v"(C10),"+v"(C11),"+v"(C12),"+v"(C13), \
     "+v"(C20),"+v"(C21),"+v"(C22),"+v"(C23), "+v"(F1a),"+v"(F1b),"+v"(F2a),"+v"(F2b), \
     "+v"(H1a),"+v"(H1b) :: "memory"); \
  f32x4 Ho0=MF(O1f[0][0],zf0,zed), Ho1=MF(O1f[1][0],zf0,zed), Ho2=MF(O1f[2][0],zf0,zed), Ho3=MF(O1f[3][0],zf0,zed); \
  f32x4 Ko0=MF(O2f[0][0],zf0,zed), Ko1=MF(O2f[1][0],zf0,zed), Ko2=MF(O2f[2][0],zf0,zed), Ko3=MF(O2f[3][0],zf0,zed); \
  Ho0=MF(O1f[0][1],zf1,Ho0); Ho1=MF(O1f[1][1],zf1,Ho1); Ho2=MF(O1f[2][1],zf1,Ho2); Ho3=MF(O1f[3][1],zf1,Ho3); \
  Ko0=MF(O2f[0][1],zf1,Ko0); Ko1=MF(O2f[1][1],zf1,Ko1); Ko2=MF(O2f[2][1],zf1,Ko2); Ko3=MF(O2f[3][1],zf1,Ko3); \
  f32x4 zA0=Gs0*rr+C10, zA1=Gs1*rr+C11, zA2=Gs2*rr+C12, zA3=Gs3*rr+C13; \
  float rr1; REDUCE_RR(zA0,zA1,zA2,zA3, rr1); \
  f32x4 Pa0,Pa1,Pa2,Pa3; UNPK(Pa0,F1a,0,1); UNPK(Pa1,F1a,2,3); UNPK(Pa2,F1b,0,1); UNPK(Pa3,F1b,2,3); \
  f32x4 Pb0,Pb1,Pb2,Pb3; UNPK(Pb0,F2a,0,1); UNPK(Pb1,F2a,2,3); UNPK(Pb2,F2b,0,1); UNPK(Pb3,F2b,2,3); \
  f32x4 Q0,Q1,Q2,Q3;     UNPK(Q0,H1a,0,1);  UNPK(Q1,H1a,2,3);  UNPK(Q2,H1b,0,1);  UNPK(Q3,H1b,2,3); \
  f32x4 T0=Q0*rr1+Pb0, T1=Q1*rr1+Pb1, T2=Q2*rr1+Pb2, T3=Q3*rr1+Pb3; \
  f32x4 H0=Gs0*D1r[0]+Ho0, H1=Gs1*D1r[1]+Ho1, H2=Gs2*D1r[2]+Ho2, H3=Gs3*D1r[3]+Ho3; \
  f32x4 Gm0=H0*rr+Pa0, Gm1=H1*rr+Pa1, Gm2=H2*rr+Pa2, Gm3=H3*rr+Pa3; \
  f32x4 zB0=Gm0*rr1+C20, zB1=Gm1*rr1+C21, zB2=Gm2*rr1+C22, zB3=Gm3*rr1+C23; \
  float rr2; REDUCE_RR(zB0,zB1,zB2,zB3, rr2); \
  f32x4 K0=Gs0*D2r[0]+Ko0, K1=Gs1*D2r[1]+Ko1, K2=Gs2*D2r[2]+Ko2, K3=Gs3*D2r[3]+Ko3; \
  float rrp=rr*rr1; \
  Gs0=K0*rrp+T0; Gs1=K1*rrp+T1; Gs2=K2*rrp+T2; Gs3=K3*rrp+T3; \
  { uint4v q0,q1; PACKZ(zA0,zA1,zA2,zA3,q0,q1); ST_Z(q0,q1, voff); } \
  { uint4v q0,q1; PACKZ(zB0,zB1,zB2,zB3,q0,q1); ST_Z(q0,q1, voff+512u); } \
  voff += 1024u; \
  LD_C (C10,C11,C12,C13, COF); LD_C2(C20,C21,C22,C23, COF); \
  LD_F (F1a,F1b, FOF, fbse); LD_F2(F2a,F2b, FOF, fbse); LD_F(H1a,H1b, FOF, hbse); \
  COF += 4096u; FOF += 2048u; \
  { uint4v p0,p1; PACKZ(Gs0,Gs1,Gs2,Gs3,p0,p1); \
    union{uint4v u; bf8 h;}cv; cv.u=p0; zf0=cv.h; cv.u=p1; zf1=cv.h; } \
  rr = rr2; \
}while(0)

  for (int i=0; i<2048; i+=2){
    ITER(cA10,cA11,cA12,cA13,cA20,cA21,cA22,cA23, fA1a,fA1b,fA2a,fA2b, hA1a,hA1b, cOfA, fOfA);
    ITER(cB10,cB11,cB12,cB13,cB20,cB21,cB22,cB23, fB1a,fB1b,fB2a,fB2b, hB1a,hB1b, cOfB, fOfB);
  }
#undef ITER
  // last iter stores ẑ4095 (real) and ẑ4096 (record 4096, dead — k_y never reads it).
  // Prefetch loads reach c token 4100 < 4112 pad, fc/ffc token 4100 < 4104 pad.
}

// ---------------------------------------------------------------- K4b: y_t = Cm_t * LN(z_t) — z bf16 chunk layout
__global__ __launch_bounds__(256) void k_y(const u16* __restrict__ zb16, const u16* __restrict__ cm,
  const float* __restrict__ stg, const float* __restrict__ stb, u16* __restrict__ y)
{
  int tid=threadIdx.x, w=tid>>6, l=tid&63;
  int token = blockIdx.x*4 + w;
  int bt = token>>12, t = token&4095;
  int gg=(l>>2)&3, mt=l>>4, rrq=l&3;
  float zv = b2f(zb16[(size_t)t*256 + (size_t)((bt*4+gg)*16 + mt*4 + rrq)]);
  float s=zv, q=zv*zv;
  for (int m2=1;m2<=32;m2<<=1){ s += __shfl_xor(s,m2,64); q += __shfl_xor(q,m2,64); }
  float mu=s*(1.f/64.f), var=q*(1.f/64.f)-mu*mu, rr=rsqrtf(var+EPS);
  float sv=(zv-mu)*rr*stg[l]+stb[l];
  y[(size_t)token*64 + l] = f2b(sv * b2f(cm[(size_t)token*64+l]));
}

// ---------------------------------------------------------------- K5: out = (y @ D_w^T + D_b) * gate
__global__ __launch_bounds__(256) void k_out(const u16* __restrict__ y, const u16* __restrict__ dw,
   const float* __restrict__ db, const u16* __restrict__ gate, float* __restrict__ out)
{
  __shared__ float tr[4][16][68];
  int tid=threadIdx.x, w=tid>>6, l=tid&63, g=l>>4, c=l&15;
  int n0=blockIdx.x*64, m0=blockIdx.y*64;
  int mrow = m0 + 16*w + c;
  bf8 af0=*(const bf8*)(y + (size_t)mrow*64 + 8*g);
  bf8 af1=*(const bf8*)(y + (size_t)mrow*64 + 32 + 8*g);
  f32x4 acc[4];
  for(int nt=0;nt<4;nt++){
    int n=n0+16*nt+c;
    bf8 b0=*(const bf8*)(dw + (size_t)n*64 + 8*g);
    bf8 b1=*(const bf8*)(dw + (size_t)n*64 + 32 + 8*g);
    f32x4 a={0,0,0,0};
    a=__builtin_amdgcn_mfma_f32_16x16x32_bf16(af0,b0,a,0,0,0);
    a=__builtin_amdgcn_mfma_f32_16x16x32_bf16(af1,b1,a,0,0,0);
    acc[nt]=a+db[n];
  }
  for(int nt=0;nt<4;nt++) for(int r=0;r<4;r++) tr[w][4*g+r][16*nt+c]=acc[nt][r];
  __syncthreads();
  int lr=l>>2, cc0=(l&3)*16;
  int grow=m0+16*w+lr;
  const u16* gp = gate + (size_t)grow*1024 + n0 + cc0;
  u16x8 g0=*(const u16x8*)(gp), g1=*(const u16x8*)(gp+8);
  float* op = out + (size_t)grow*1024 + n0 + cc0;
  float vv[16];
  for(int j2=0;j2<16;j2++){
    u16 gb16 = (j2<8)? g0[j2] : g1[j2-8];
    vv[j2]=tr[w][lr][cc0+j2]*b2f(gb16);
  }
  for(int j2=0;j2<4;j2++){
    f32x4 ov={vv[4*j2],vv[4*j2+1],vv[4*j2+2],vv[4*j2+3]};
    *(f32x4*)(op+4*j2)=ov;
  }
}

// ----------------------------------------------------------------
extern "C" void kernel_launch(void* const* d_in, const int* in_sizes, int n_in,
                              void* d_out, int out_size, void* d_ws, size_t ws_size,
                              hipStream_t stream) {
  const float* x=(const float*)d_in[0];
  const float* A=(const float*)d_in[1];
  const float* dt=(const float*)d_in[2];
  const float* B_w=(const float*)d_in[3];
  const float* B_b=(const float*)d_in[4];
  const float* C_w=(const float*)d_in[5];
  const float* C_b=(const float*)d_in[6];
  const float* D_w=(const float*)d_in[7];
  const float* D_b=(const float*)d_in[8];
  const float* conv_w=(const float*)d_in[9];
  const float* conv_b=(const float*)d_in[10];
  const float* gate_w=(const float*)d_in[11];
  const float* gate_b=(const float*)d_in[12];
  const float* ln_in_g=(const float*)d_in[13];
  const float* ln_in_b=(const float*)d_in[14];
  const float* ln_st_g=(const float*)d_in[15];
  const float* ln_st_b=(const float*)d_in[16];
  char* ws=(char*)d_ws;
  u16* xn   =(u16*)(ws);                    // 33,554,432
  u16* xg   =(u16*)(ws+33554432);           // 33,554,432
  u16* gate =(u16*)(ws+67108864);           // 33,554,432
  u16* gwb  =(u16*)(ws+100663296);          // 4,194,304
  u16* bwb  =(u16*)(ws+104857600);          // 131,072
  u16* cwb  =(u16*)(ws+104988672);          // 131,072
  u16* dwb  =(u16*)(ws+105119744);          // 131,072
  u16* cm   =(u16*)(ws+105250816);          // 2,097,152
  float* c_ws=(float*)(ws+107347968);       // 4112*1024B = 4,210,688
  // old z region (16MB at 111558656) subdivided: bf16 z | fc | ffc | M1 | M2 | dcm
  u16* zb16  =(u16*)(ws+111558656);                 // 4097*512B (4MB reserved)
  u16* fc_ws =(u16*)(ws+111558656+4194304);         // 4104*512B = 2,101,248
  u16* ffc_ws=(u16*)(ws+111558656+6295552);         // 4104*512B = 2,101,248
  float* m1g =(float*)(ws+111558656+8396800);       // 16,384
  float* m2g =(float*)(ws+111558656+8413184);       // 16,384
  float* dcm =(float*)(ws+111558656+8429568);       // 512 B: D1[64] + D2[64]  (moved OUT of ft)
  u16* y    =(u16*)(ws+128335872);          // 2,097,152
  float* abeta=(float*)(ws+130433024);      // 256
  u16* ft   =(u16*)(ws+130433280);          // 16,384 (O1 | O2 tables)
  float* out=(float*)d_out;

  hipLaunchKernelGGL(k_prep,  dim3(1),      dim3(1024),0,stream, A, dt, ln_st_g, ln_st_b, abeta, ft, dcm, m1g, m2g);
  hipLaunchKernelGGL(k_wcvt,  dim3(8960),   dim3(256), 0,stream, gate_w,B_w,C_w,D_w, gwb,bwb,cwb,dwb);
  hipLaunchKernelGGL(k_lnconv,dim3(2048),   dim3(256), 0,stream, x, ln_in_g, ln_in_b, conv_w, conv_b, xn);
  hipLaunchKernelGGL(k_gate,  dim3(16,128), dim3(256), 0,stream, xn,gwb,gate_b,gate,xg);
  hipLaunchKernelGGL(k_bc,    dim3(256),    dim3(256), 0,stream, xg,xn,bwb,cwb,B_b,C_b,abeta,c_ws,cm);
  hipLaunchKernelGGL(k_fc,    dim3(256),    dim3(256), 0,stream, c_ws, m1g, m2g, fc_ws, ffc_ws);
  hipLaunchKernelGGL(k_scan,  dim3(1),      dim3(64),  0,stream, c_ws, ft, dcm, fc_ws, ffc_ws, zb16);
  hipLaunchKernelGGL(k_y,     dim3(4096),   dim3(256), 0,stream, zb16,cm,ln_st_g,ln_st_b,y);
  hipLaunchKernelGGL(k_out,   dim3(16,256), dim3(256), 0,stream, y,dwb,D_b,gate,out);
}

// Round 11
// 1714.777 us; speedup vs baseline: 1.3353x; 1.3353x over previous
//
#include <hip/hip_runtime.h>
#include <cstdint>

#define EPS 1e-5f
typedef float f32x4 __attribute__((ext_vector_type(4)));
typedef short bf8 __attribute__((ext_vector_type(8)));   // 8 bf16 vals (4 VGPRs)
typedef unsigned short u16;
typedef unsigned short u16x8 __attribute__((ext_vector_type(8)));
typedef unsigned int uint4v __attribute__((ext_vector_type(4)));

__device__ __forceinline__ u16 f2b(float f){
  unsigned x = __float_as_uint(f);
  unsigned r = x + 0x7FFFu + ((x>>16)&1u);   // round-to-nearest-even
  return (u16)(r>>16);
}
__device__ __forceinline__ float b2f(u16 h){ return __uint_as_float(((unsigned)h)<<16); }
// pack two f32 -> one dword of 2 bf16 (a in low half); round-half-up (ties differ from RNE only)
__device__ __forceinline__ unsigned pk2(float a, float b){
  unsigned ua = __float_as_uint(a) + 0x8000u;
  unsigned ub = __float_as_uint(b) + 0x8000u;
  return __builtin_amdgcn_perm(ub, ua, 0x07060302u);
}

#define GLL(gp, lp) __builtin_amdgcn_global_load_lds((__attribute__((address_space(1))) const void*)(gp), (__attribute__((address_space(3))) void*)(lp), 16, 0, 0)

// ---------------------------------------------------------------- K0a: expm + Mhat hi/lo fragment table
__global__ __launch_bounds__(1024) void k_prep(const float* __restrict__ A, const float* __restrict__ dtp,
    const float* __restrict__ stg, const float* __restrict__ stb,
    float* __restrict__ abeta, u16* __restrict__ ft)
{
  __shared__ float M[4096], Ta[4096], Tb[4096], P[4096];
  __shared__ float cmn[64];
  int tid = threadIdx.x;
  float dt = dtp[0];
  for (int e=tid; e<4096; e+=1024){
    float v = dt * A[e];
    int i = e>>6, j = e&63;
    M[e] = v;
    P[e] = v + (i==j ? 1.0f : 0.0f);
    Ta[e] = v;
  }
  __syncthreads();
  float* src = Ta; float* dst = Tb;
  for (int k=2;k<=14;k++){
    float inv = 1.0f/(float)k;
    int i = tid>>4, j0 = (tid&15)*4;
    float a0=0,a1=0,a2=0,a3=0;
    for (int m2=0;m2<64;m2++){
      float f = src[i*64+m2];
      const float* Mr = &M[m2*64+j0];
      a0 += f*Mr[0]; a1 += f*Mr[1]; a2 += f*Mr[2]; a3 += f*Mr[3];
    }
    a0*=inv; a1*=inv; a2*=inv; a3*=inv;
    int base=i*64+j0;
    dst[base+0]=a0; dst[base+1]=a1; dst[base+2]=a2; dst[base+3]=a3;
    P[base+0]+=a0; P[base+1]+=a1; P[base+2]+=a2; P[base+3]+=a3;
    __syncthreads();
    float* tmp=src; src=dst; dst=tmp;
  }
  if (tid<64){
    float c0=0, ab=0; int p = tid;
    for (int q2=0;q2<64;q2++){ float ap = P[q2*64+p]; c0 += stg[q2]*ap; ab += stb[q2]*ap; }
    cmn[p] = c0*(1.0f/64.0f);
    abeta[p] = ab;
  }
  __syncthreads();
  for (int e=tid; e<4096; e+=1024){
    int q2=e>>6, p=e&63;
    Ta[e] = stg[q2]*P[q2*64+p] - cmn[p];
  }
  __syncthreads();
  // fragment table: A-operand of MFMA (W2[p][q] = Mhat[q][p]), hi/lo bf16 split (systematic
  // weight-quantization error pumps near-unit modes of A_bar coherently -> must be ~fp32).
  for (int ii=0; ii<4; ii++){
    int e = tid*4+ii;
    int j = e&7, l = (e>>3)&63, kt=(e>>9)&1, mt=e>>10;
    int q2 = 16*(2*kt + (j>>2)) + 4*(l>>4) + (j&3);
    int p = 16*mt + (l&15);
    float v = Ta[q2*64+p];
    u16 hi = f2b(v);
    float lo = v - b2f(hi);
    ft[e] = hi;
    ft[e+4096] = f2b(lo);
  }
}

// ---------------------------------------------------------------- K0b: weights -> bf16 (R15: x4 vectorized)
__global__ __launch_bounds__(256) void k_wcvt(const float* __restrict__ gw, const float* __restrict__ bw,
   const float* __restrict__ cw, const float* __restrict__ dw,
   u16* __restrict__ ogw, u16* __restrict__ obw, u16* __restrict__ ocw, u16* __restrict__ odw)
{
  int n = (blockIdx.x*256 + threadIdx.x)*4;   // all segment boundaries divisible by 4
  const float* src; u16* dst; int off;
  if (n < 2097152){ src=gw; dst=ogw; off=n; }
  else if (n < 2162688){ src=bw; dst=obw; off=n-2097152; }
  else if (n < 2228224){ src=cw; dst=ocw; off=n-2162688; }
  else { src=dw; dst=odw; off=n-2228224; }
  f32x4 v = *(const f32x4*)(src+off);
  uint2 pkv;
  pkv.x = (unsigned)f2b(v.x) | ((unsigned)f2b(v.y)<<16);
  pkv.y = (unsigned)f2b(v.z) | ((unsigned)f2b(v.w)<<16);
  *(uint2*)(dst+off) = pkv;
}

// ---------------------------------------------------------------- K1: layernorm + depthwise conv + residual -> bf16
__global__ __launch_bounds__(256) void k_lnconv(const float* __restrict__ x, const float* __restrict__ gin,
  const float* __restrict__ bin, const float* __restrict__ cwt, const float* __restrict__ cb, u16* __restrict__ xn)
{
  __shared__ float red[10][8];
  int tid = threadIdx.x; int w = tid>>6; int lane = tid&63;
  int r0 = blockIdx.x*8;
  int bt = r0>>12, t0 = r0&4095;
  int c4 = tid*4;
  f32x4 g4 = *(const f32x4*)(gin + c4);
  f32x4 b4 = *(const f32x4*)(bin + c4);
  f32x4 vals[10];
  for (int lr=0; lr<10; lr++){
    int t = t0 - 1 + lr;
    f32x4 xv = {0,0,0,0};
    bool ok = (t>=0 && t<4096);
    if (ok) xv = *(const f32x4*)(x + (size_t)(bt*4096+t)*1024 + c4);
    float s = xv.x+xv.y+xv.z+xv.w;
    float q = xv.x*xv.x+xv.y*xv.y+xv.z*xv.z+xv.w*xv.w;
    for (int m2=1;m2<=32;m2<<=1){ s += __shfl_xor(s,m2,64); q += __shfl_xor(q,m2,64); }
    if (lane==0){ red[lr][w]=s; red[lr][4+w]=q; }
    __syncthreads();
    s = red[lr][0]+red[lr][1]+red[lr][2]+red[lr][3];
    q = red[lr][4]+red[lr][5]+red[lr][6]+red[lr][7];
    float mu = s*(1.f/1024.f);
    float var = q*(1.f/1024.f) - mu*mu;
    float rr = rsqrtf(var + EPS);
    f32x4 o = {0,0,0,0};
    if (ok){
      o.x=(xv.x-mu)*rr*g4.x+b4.x; o.y=(xv.y-mu)*rr*g4.y+b4.y;
      o.z=(xv.z-mu)*rr*g4.z+b4.z; o.w=(xv.w-mu)*rr*g4.w+b4.w;
    }
    vals[lr]=o;
  }
  float w0[4], w1[4], w2[4], cbv[4];
  for (int ii=0;ii<4;ii++){ int c = c4+ii; w0[ii]=cwt[c*3+0]; w1[ii]=cwt[c*3+1]; w2[ii]=cwt[c*3+2]; cbv[ii]=cb[c]; }
  for (int lr=1; lr<=8; lr++){
    int t = t0 + lr - 1;
    f32x4 o;
    o.x = vals[lr].x + w0[0]*vals[lr-1].x + w1[0]*vals[lr].x + w2[0]*vals[lr+1].x + cbv[0];
    o.y = vals[lr].y + w0[1]*vals[lr-1].y + w1[1]*vals[lr].y + w2[1]*vals[lr+1].y + cbv[1];
    o.z = vals[lr].z + w0[2]*vals[lr-1].z + w1[2]*vals[lr].z + w2[2]*vals[lr+1].z + cbv[2];
    o.w = vals[lr].w + w0[3]*vals[lr-1].w + w1[3]*vals[lr].w + w2[3]*vals[lr+1].w + cbv[3];
    size_t off = (size_t)(bt*4096+t)*1024 + c4;
    unsigned lo2 = (unsigned)f2b(o.x) | ((unsigned)f2b(o.y)<<16);
    unsigned hi2 = (unsigned)f2b(o.z) | ((unsigned)f2b(o.w)<<16);
    uint2 pk; pk.x=lo2; pk.y=hi2;
    *(uint2*)(xn + off) = pk;
  }
}

// ---------------------------------------------------------------- K2: gate GEMM + sigmoid + xg
// R6 epilogue: XCD-chunk swizzle; LDS f32 transpose stage -> whole-line dwordx4 stores;
// vectorized xn reads. (was 65x write amplification, 1400us -> below scan)
__global__ __launch_bounds__(256) void k_gate(const u16* __restrict__ xn, const u16* __restrict__ gw,
    const float* __restrict__ gb, u16* __restrict__ gate_o, u16* __restrict__ xg_o)
{
  __shared__ char smem[33792];          // As(8K)+Bs(8K) during K-loop; st(64x132 f32) after
  u16* As = (u16*)smem;
  u16* Bs = (u16*)(smem + 8192);
  float* st = (float*)smem;
  int tid=threadIdx.x, w=tid>>6, l=tid&63;
  int flat = blockIdx.x + (int)gridDim.x*blockIdx.y;    // 2048 blocks, %8==0
  int logical = (flat&7)*256 + (flat>>3);
  int n0 = (logical&15)*128, m0 = (logical>>4)*128;
  int wr = w>>1, wc = w&1;
  f32x4 acc[4][4] = {};
  for (int kk=0; kk<32; kk++){
    int k0 = kk*32;
    for (int i2=0;i2<2;i2++){
      const char* ga = (const char*)xn + ((size_t)(m0+32*w+16*i2+(l>>2))*1024 + k0)*2 + (l&3)*16;
      GLL(ga, (char*)As + (32*w+16*i2)*64);
      const char* gbp = (const char*)gw + ((size_t)(n0+32*w+16*i2+(l>>2))*1024 + k0)*2 + (l&3)*16;
      GLL(gbp, (char*)Bs + (32*w+16*i2)*64);
    }
    __syncthreads();
    bf8 af[4], bfr[4];
    for (int mt=0;mt<4;mt++) af[mt] = *(const bf8*)(As + (wr*64+mt*16+(l&15))*32 + 8*(l>>4));
    for (int nt=0;nt<4;nt++) bfr[nt] = *(const bf8*)(Bs + (wc*64+nt*16+(l&15))*32 + 8*(l>>4));
    for (int mt=0;mt<4;mt++) for (int nt=0;nt<4;nt++)
      acc[mt][nt] = __builtin_amdgcn_mfma_f32_16x16x32_bf16(af[mt], bfr[nt], acc[mt][nt], 0,0,0);
    __syncthreads();
  }
  // ---- epilogue: two 64-row passes; pass p stages waves wr==p through LDS
  bool isxg = (n0 >= 1024);
  int r2 = tid>>2, q = tid&3;          // r2: row within pass (0..63), q: 32-col quarter
  f32x4 gb4[8];
  for (int j=0;j<8;j++) gb4[j] = *(const f32x4*)(gb + n0 + q*32 + j*4);
  int g = l>>4, c = l&15;
  for (int p=0;p<2;p++){
    __syncthreads();
    if (wr==p){
      for (int mt=0;mt<4;mt++) for (int nt=0;nt<4;nt++)
        for (int r=0;r<4;r++)
          st[(mt*16+4*g+r)*132 + wc*64+nt*16+c] = acc[mt][nt][r];
    }
    __syncthreads();
    int row = m0 + p*64 + r2;
    const float* sp = st + r2*132 + q*32;
    u16 ob[32];
    if (!isxg){
      for (int j=0;j<8;j++){
        f32x4 v = *(const f32x4*)(sp + 4*j);
        v = v + gb4[j];
        ob[4*j+0] = f2b(1.0f/(1.0f+__expf(-v.x)));
        ob[4*j+1] = f2b(1.0f/(1.0f+__expf(-v.y)));
        ob[4*j+2] = f2b(1.0f/(1.0f+__expf(-v.z)));
        ob[4*j+3] = f2b(1.0f/(1.0f+__expf(-v.w)));
      }
    } else {
      const u16* xp = xn + (size_t)row*1024 + (n0-1024) + q*32;
      u16 xb[32];
      for (int j=0;j<4;j++){
        u16x8 t8 = *(const u16x8*)(xp + 8*j);
        for (int e=0;e<8;e++) xb[8*j+e] = t8[e];
      }
      for (int j=0;j<8;j++){
        f32x4 v = *(const f32x4*)(sp + 4*j);
        v = v + gb4[j];
        ob[4*j+0] = f2b(b2f(xb[4*j+0]) * (1.0f/(1.0f+__expf(-v.x))));
        ob[4*j+1] = f2b(b2f(xb[4*j+1]) * (1.0f/(1.0f+__expf(-v.y))));
        ob[4*j+2] = f2b(b2f(xb[4*j+2]) * (1.0f/(1.0f+__expf(-v.z))));
        ob[4*j+3] = f2b(b2f(xb[4*j+3]) * (1.0f/(1.0f+__expf(-v.w))));
      }
    }
    u16* op = isxg ? (xg_o + (size_t)row*1024 + (n0-1024) + q*32)
                   : (gate_o + (size_t)row*1024 + n0 + q*32);
    unsigned od[16];
    for (int i2=0;i2<16;i2++) od[i2] = (unsigned)ob[2*i2] | ((unsigned)ob[2*i2+1]<<16);
    uint4v s0 = {od[0],od[1],od[2],od[3]};
    uint4v s1 = {od[4],od[5],od[6],od[7]};
    uint4v s2 = {od[8],od[9],od[10],od[11]};
    uint4v s3 = {od[12],od[13],od[14],od[15]};
    *(uint4v*)(op+ 0) = s0;
    *(uint4v*)(op+ 8) = s1;
    *(uint4v*)(op+16) = s2;
    *(uint4v*)(op+24) = s3;
  }
}

// ---------------------------------------------------------------- K3: Bm (-> c_ws, scan layout) and Cm (bf16)
__global__ __launch_bounds__(256) void k_bc(const u16* __restrict__ xg, const u16* __restrict__ xn,
   const u16* __restrict__ bw, const u16* __restrict__ cw,
   const float* __restrict__ bb, const float* __restrict__ cbias_, const float* __restrict__ abeta,
   float* __restrict__ c_ws, u16* __restrict__ cm)
{
  __shared__ u16 As[128*32], Bs[64*32];
  int tid=threadIdx.x, w=tid>>6, l=tid&63;
  int id = blockIdx.x; int half = id>>7; int m0 = (id&127)*128;
  const u16* Ap = half ? xn : xg;
  const u16* Bp = half ? cw : bw;
  f32x4 acc[2][4]={};
  for (int kk=0;kk<32;kk++){
    int k0=kk*32;
    for (int i2=0;i2<2;i2++){
      const char* ga=(const char*)Ap + ((size_t)(m0+32*w+16*i2+(l>>2))*1024+k0)*2+(l&3)*16;
      GLL(ga, (char*)As+(32*w+16*i2)*64);
    }
    { const char* gbp=(const char*)Bp + ((size_t)(16*w+(l>>2))*1024+k0)*2+(l&3)*16;
      GLL(gbp, (char*)Bs+(16*w)*64); }
    __syncthreads();
    bf8 af[2], bfr[4];
    for (int mt=0;mt<2;mt++) af[mt]=*(const bf8*)(As+(32*w+16*mt+(l&15))*32+8*(l>>4));
    for (int nt=0;nt<4;nt++) bfr[nt]=*(const bf8*)(Bs+(16*nt+(l&15))*32+8*(l>>4));
    for (int mt=0;mt<2;mt++) for(int nt=0;nt<4;nt++)
      acc[mt][nt]=__builtin_amdgcn_mfma_f32_16x16x32_bf16(af[mt],bfr[nt],acc[mt][nt],0,0,0);
    __syncthreads();
  }
  int g=l>>4, c=l&15;
  if (half==0){
    for (int nt=0;nt<4;nt++){ int n=16*nt+c; float bias=bb[n]; float ab=abeta[n];
      for(int mt=0;mt<2;mt++) for(int r=0;r<4;r++){
        int row=m0+32*w+16*mt+4*g+r; int bt=row>>12, t=row&4095;
        float v=acc[mt][nt][r]+bias + (t>0?ab:0.0f);
        c_ws[(size_t)t*256 + bt*64 + n] = v;
      }
    }
  } else {
    for (int nt=0;nt<4;nt++){ int n=16*nt+c; float bias=cbias_[n];
      for(int mt=0;mt<2;mt++) for(int r=0;r<4;r++){
        int row=m0+32*w+16*mt+4*g+r;
        cm[(size_t)row*64+n]=f2b(acc[mt][nt][r]+bias);
      }
    }
  }
}

// ---------------------------------------------------------------- K4: sequential scan — one wave, all 4 batches.
// R15 = reversion to the session-best R6/R5 structure (1317us measured): commuted-scalar
// recurrence (rr applied after MFMA), hi/lo Wh/Wl 16 MFMAs (4 chains depth 4), GLL ring
// (9-slot lead, vmcnt(24)), ds_read hoisted to step start, LN reduce hidden under chain.
// Scan-floor ledger: R7 depth-2 1442, R8 spinners 1545, R9 vmcnt-slack 1332, R11 no-GLL
// 1509, R14 2-token 1897 — the ~780cy/token floor is the recurrence's serial chain
// (apply-rr -> pack -> MFMA -> reduce -> rsqrt) under single-wave hazard latencies;
// no instruction-level or algebraic lever beat this structure.
__global__ __launch_bounds__(64,1) void k_scan(const float* __restrict__ c_ws, const u16* __restrict__ ft,
  float* __restrict__ z_ws)
{
  __shared__ float ring[16*256];   // 16 slots x 1024 B
  int l=threadIdx.x, g=l>>4, b=l&3;
  const bf8* ftv=(const bf8*)ft;
  bf8 Wh[4][2], Wl[4][2];
  for(int mt=0;mt<4;mt++)for(int kt=0;kt<2;kt++){
    Wh[mt][kt]=ftv[(mt*2+kt)*64+l];
    Wl[mt][kt]=ftv[(8+mt*2+kt)*64+l];
  }
  const f32x4 zed = {0.f,0.f,0.f,0.f};
  f32x4 z0,z1,z2,z3;
  {
    const float* zp = c_ws + b*64 + 4*g;   // t=0: z_0 = c_0 (K3 omitted abeta at t==0)
    z0=*(const f32x4*)(zp+0); z1=*(const f32x4*)(zp+16); z2=*(const f32x4*)(zp+32); z3=*(const f32x4*)(zp+48);
  }
  for(int u2=1;u2<=8;u2++){
    const char* ga=(const char*)c_ws + (size_t)u2*1024 + l*16;
    GLL(ga, (char*)ring + u2*1024);
  }
  asm volatile("s_waitcnt vmcnt(0)" ::: "memory");
  unsigned laneoff;
  {
    __attribute__((address_space(3))) float* l3=( __attribute__((address_space(3))) float*)ring;
    laneoff=(unsigned)(uintptr_t)l3 + (unsigned)(b*256 + g*16);
  }
  // z store layout (fp32): z_ws[t*1024 + col*64 + 16*mt + 4*g + r], col=l&15
  unsigned voff = (unsigned)(((l&15)*64 + 4*g)*4);
  unsigned long long zb = (unsigned long long)(uintptr_t)z_ws;
  f32x4 cN0,cN1,cN2,cN3;
  bf8 zf0, zf1;

  // ---- prologue: pack zf_0 = bf16(z_0) (RAW, unnormalized). NO store here —
  // step t's phase 4 stores z_t at slot t (voff starts at slot 0).
  {
    uint4v p0,p1;
    p0.x=pk2(z0.x,z0.y); p0.y=pk2(z0.z,z0.w); p0.z=pk2(z1.x,z1.y); p0.w=pk2(z1.z,z1.w);
    p1.x=pk2(z2.x,z2.y); p1.y=pk2(z2.z,z2.w); p1.z=pk2(z3.x,z3.y); p1.w=pk2(z3.z,z3.w);
    { union { uint4v u; bf8 h; } cv; cv.u=p0; zf0=cv.h; cv.u=p1; zf1=cv.h; }
  }

  unsigned slotr = 1024u;          // ring byte offset of slot (t+1)&15 (t=0 -> slot 1)
  unsigned ldst  = 9u*1024u;       // ring byte offset of slot (t+9)&15 (t=0 -> slot 9)
  const char* gsrc = (const char*)c_ws + (size_t)9*1024;   // token t+9

  // per-step vm ops: 1 GLL then 4 stores. GLL for the slot read at step t was issued at
  // step t-8 with 39 newer vm-ops at this wait -> vmcnt(24) <= 39 -> safe.
  for (int t=0; t<4096; ++t){
    // ---- phase 1: prefetches (latency hidden by whole step body)
    asm volatile("s_waitcnt vmcnt(24)" ::: "memory");
    { unsigned ro = laneoff + slotr;
      asm volatile("ds_read_b128 %0, %4 offset:0\n\t"
                   "ds_read_b128 %1, %4 offset:64\n\t"
                   "ds_read_b128 %2, %4 offset:128\n\t"
                   "ds_read_b128 %3, %4 offset:192"
                   : "=v"(cN0),"=v"(cN1),"=v"(cN2),"=v"(cN3) : "v"(ro) : "memory"); }
    GLL(gsrc + (size_t)l*16, (char*)ring + ldst);
    // ---- phase 2: u = W·zf, 4 independent chains of depth 4 (R1-proven shape, acc init 0)
    f32x4 u0=__builtin_amdgcn_mfma_f32_16x16x32_bf16(Wh[0][0],zf0,zed,0,0,0);
    f32x4 u1=__builtin_amdgcn_mfma_f32_16x16x32_bf16(Wh[1][0],zf0,zed,0,0,0);
    f32x4 u2=__builtin_amdgcn_mfma_f32_16x16x32_bf16(Wh[2][0],zf0,zed,0,0,0);
    f32x4 u3=__builtin_amdgcn_mfma_f32_16x16x32_bf16(Wh[3][0],zf0,zed,0,0,0);
    u0=__builtin_amdgcn_mfma_f32_16x16x32_bf16(Wh[0][1],zf1,u0,0,0,0);
    u1=__builtin_amdgcn_mfma_f32_16x16x32_bf16(Wh[1][1],zf1,u1,0,0,0);
    u2=__builtin_amdgcn_mfma_f32_16x16x32_bf16(Wh[2][1],zf1,u2,0,0,0);
    u3=__builtin_amdgcn_mfma_f32_16x16x32_bf16(Wh[3][1],zf1,u3,0,0,0);
    u0=__builtin_amdgcn_mfma_f32_16x16x32_bf16(Wl[0][0],zf0,u0,0,0,0);
    u1=__builtin_amdgcn_mfma_f32_16x16x32_bf16(Wl[1][0],zf0,u1,0,0,0);
    u2=__builtin_amdgcn_mfma_f32_16x16x32_bf16(Wl[2][0],zf0,u2,0,0,0);
    u3=__builtin_amdgcn_mfma_f32_16x16x32_bf16(Wl[3][0],zf0,u3,0,0,0);
    u0=__builtin_amdgcn_mfma_f32_16x16x32_bf16(Wl[0][1],zf1,u0,0,0,0);
    u1=__builtin_amdgcn_mfma_f32_16x16x32_bf16(Wl[1][1],zf1,u1,0,0,0);
    u2=__builtin_amdgcn_mfma_f32_16x16x32_bf16(Wl[2][1],zf1,u2,0,0,0);
    u3=__builtin_amdgcn_mfma_f32_16x16x32_bf16(Wl[3][1],zf1,u3,0,0,0);
    // ---- phase 3: LN reduce of current z -> rr (overlaps MFMA chain latency)
    float rr;
    {
      f32x4 s4=(z0+z1)+(z2+z3);
      float s=(s4.x+s4.y)+(s4.z+s4.w);
      f32x4 qa=z0*z0; qa=z1*z1+qa;
      f32x4 qb=z2*z2; qb=z3*z3+qb;
      f32x4 q4=qa+qb;
      float q=(q4.x+q4.y)+(q4.z+q4.w);
      float sB=s, qB=q;
      asm("v_permlane16_swap_b32 %0, %1" : "+v"(s), "+v"(sB));
      asm("v_permlane16_swap_b32 %0, %1" : "+v"(q), "+v"(qB));
      s+=sB; q+=qB;
      float sC=s, qC=q;
      asm("v_permlane32_swap_b32 %0, %1" : "+v"(s), "+v"(sC));
      asm("v_permlane32_swap_b32 %0, %1" : "+v"(q), "+v"(qC));
      s+=sC; q+=qC;
      float mu=s*(1.f/64.f);
      float var=q*(1.f/64.f)-mu*mu;
      rr=rsqrtf(var+EPS);
    }
    // ---- phase 4: store current z_t at slot t (fire-and-forget)
    asm volatile("global_store_dwordx4 %0, %1, %5\n\t"
                 "global_store_dwordx4 %0, %2, %5 offset:64\n\t"
                 "global_store_dwordx4 %0, %3, %5 offset:128\n\t"
                 "global_store_dwordx4 %0, %4, %5 offset:192"
                 :: "v"(voff), "v"(z0), "v"(z1), "v"(z2), "v"(z3), "s"(zb) : "memory");
    voff += 4096u;
    // ---- phase 5: pointer/slot updates (off critical path)
    slotr = (slotr + 1024u) & 16383u;
    ldst  = (ldst  + 1024u) & 16383u;
    gsrc += 1024;
    // ---- phase 6: z' = u*rr + c  (rr commuted out of the matmul)
    asm volatile("s_waitcnt lgkmcnt(0)" : "+v"(cN0),"+v"(cN1),"+v"(cN2),"+v"(cN3) :: "memory");
    z0 = u0*rr + cN0;
    z1 = u1*rr + cN1;
    z2 = u2*rr + cN2;
    z3 = u3*rr + cN3;
    // ---- phase 7: pack zf = bf16(z') raw
    uint4v p0,p1;
    p0.x=pk2(z0.x,z0.y); p0.y=pk2(z0.z,z0.w); p0.z=pk2(z1.x,z1.y); p0.w=pk2(z1.z,z1.w);
    p1.x=pk2(z2.x,z2.y); p1.y=pk2(z2.z,z2.w); p1.z=pk2(z3.x,z3.y); p1.w=pk2(z3.z,z3.w);
    { union { uint4v u; bf8 h; } cv; cv.u=p0; zf0=cv.h; cv.u=p1; zf1=cv.h; }
  }
  // final iteration (t=4095) stores z_4095 (last in-bounds slot); z_4096 is computed into
  // registers but never stored. GLL prefetches reach token 4104 < 4112 (c_ws padding).
}

// ---------------------------------------------------------------- K4b: y_t = Cm_t * LN(z_t)  (parallel over tokens)
__global__ __launch_bounds__(256) void k_y(const float* __restrict__ z_ws, const u16* __restrict__ cm,
  const float* __restrict__ stg, const float* __restrict__ stb, u16* __restrict__ y)
{
  int tid=threadIdx.x, w=tid>>6, l=tid&63;
  int token = blockIdx.x*4 + w;
  int bt = token>>12, t = token&4095;
  float zv = z_ws[(size_t)t*1024 + bt*64 + l];
  float s=zv, q=zv*zv;
  for (int m2=1;m2<=32;m2<<=1){ s += __shfl_xor(s,m2,64); q += __shfl_xor(q,m2,64); }
  float mu=s*(1.f/64.f), var=q*(1.f/64.f)-mu*mu, rr=rsqrtf(var+EPS);
  float sv=(zv-mu)*rr*stg[l]+stb[l];
  y[(size_t)token*64 + l] = f2b(sv * b2f(cm[(size_t)token*64+l]));
}

// ---------------------------------------------------------------- K5: out = (y @ D_w^T + D_b) * gate
__global__ __launch_bounds__(256) void k_out(const u16* __restrict__ y, const u16* __restrict__ dw,
   const float* __restrict__ db, const u16* __restrict__ gate, float* __restrict__ out)
{
  __shared__ float tr[4][16][68];
  int tid=threadIdx.x, w=tid>>6, l=tid&63, g=l>>4, c=l&15;
  int n0=blockIdx.x*64, m0=blockIdx.y*64;
  int mrow = m0 + 16*w + c;
  bf8 af0=*(const bf8*)(y + (size_t)mrow*64 + 8*g);
  bf8 af1=*(const bf8*)(y + (size_t)mrow*64 + 32 + 8*g);
  f32x4 acc[4];
  for(int nt=0;nt<4;nt++){
    int n=n0+16*nt+c;
    bf8 b0=*(const bf8*)(dw + (size_t)n*64 + 8*g);
    bf8 b1=*(const bf8*)(dw + (size_t)n*64 + 32 + 8*g);
    f32x4 a={0,0,0,0};
    a=__builtin_amdgcn_mfma_f32_16x16x32_bf16(af0,b0,a,0,0,0);
    a=__builtin_amdgcn_mfma_f32_16x16x32_bf16(af1,b1,a,0,0,0);
    acc[nt]=a+db[n];
  }
  for(int nt=0;nt<4;nt++) for(int r=0;r<4;r++) tr[w][4*g+r][16*nt+c]=acc[nt][r];
  __syncthreads();
  int lr=l>>2, cc0=(l&3)*16;
  int grow=m0+16*w+lr;
  const u16* gp = gate + (size_t)grow*1024 + n0 + cc0;
  u16x8 g0=*(const u16x8*)(gp), g1=*(const u16x8*)(gp+8);
  float* op = out + (size_t)grow*1024 + n0 + cc0;
  float vv[16];
  for(int j2=0;j2<16;j2++){
    u16 gb16 = (j2<8)? g0[j2] : g1[j2-8];
    vv[j2]=tr[w][lr][cc0+j2]*b2f(gb16);
  }
  for(int j2=0;j2<4;j2++){
    f32x4 ov={vv[4*j2],vv[4*j2+1],vv[4*j2+2],vv[4*j2+3]};
    *(f32x4*)(op+4*j2)=ov;
  }
}

// ----------------------------------------------------------------
extern "C" void kernel_launch(void* const* d_in, const int* in_sizes, int n_in,
                              void* d_out, int out_size, void* d_ws, size_t ws_size,
                              hipStream_t stream) {
  const float* x=(const float*)d_in[0];
  const float* A=(const float*)d_in[1];
  const float* dt=(const float*)d_in[2];
  const float* B_w=(const float*)d_in[3];
  const float* B_b=(const float*)d_in[4];
  const float* C_w=(const float*)d_in[5];
  const float* C_b=(const float*)d_in[6];
  const float* D_w=(const float*)d_in[7];
  const float* D_b=(const float*)d_in[8];
  const float* conv_w=(const float*)d_in[9];
  const float* conv_b=(const float*)d_in[10];
  const float* gate_w=(const float*)d_in[11];
  const float* gate_b=(const float*)d_in[12];
  const float* ln_in_g=(const float*)d_in[13];
  const float* ln_in_b=(const float*)d_in[14];
  const float* ln_st_g=(const float*)d_in[15];
  const float* ln_st_b=(const float*)d_in[16];
  char* ws=(char*)d_ws;
  u16* xn   =(u16*)(ws);                    // 33,554,432
  u16* xg   =(u16*)(ws+33554432);           // 33,554,432
  u16* gate =(u16*)(ws+67108864);           // 33,554,432
  u16* gwb  =(u16*)(ws+100663296);          // 4,194,304
  u16* bwb  =(u16*)(ws+104857600);          // 131,072
  u16* cwb  =(u16*)(ws+104988672);          // 131,072
  u16* dwb  =(u16*)(ws+105119744);          // 131,072
  u16* cm   =(u16*)(ws+105250816);          // 2,097,152
  float* c_ws=(float*)(ws+107347968);       // 4112*1024B = 4,210,688
  float* z_ws=(float*)(ws+111558656);       // 16,777,216 (fp32 z)
  u16* y    =(u16*)(ws+128335872);          // 2,097,152
  float* abeta=(float*)(ws+130433024);      // 256
  u16* ft   =(u16*)(ws+130433280);          // 16,384
  float* out=(float*)d_out;

  hipLaunchKernelGGL(k_prep,  dim3(1),      dim3(1024),0,stream, A, dt, ln_st_g, ln_st_b, abeta, ft);
  hipLaunchKernelGGL(k_wcvt,  dim3(2240),   dim3(256), 0,stream, gate_w,B_w,C_w,D_w, gwb,bwb,cwb,dwb);
  hipLaunchKernelGGL(k_lnconv,dim3(2048),   dim3(256), 0,stream, x, ln_in_g, ln_in_b, conv_w, conv_b, xn);
  hipLaunchKernelGGL(k_gate,  dim3(16,128), dim3(256), 0,stream, xn,gwb,gate_b,gate,xg);
  hipLaunchKernelGGL(k_bc,    dim3(256),    dim3(256), 0,stream, xg,xn,bwb,cwb,B_b,C_b,abeta,c_ws,cm);
  hipLaunchKernelGGL(k_scan,  dim3(1),      dim3(64),  0,stream, c_ws, ft, z_ws);
  hipLaunchKernelGGL(k_y,     dim3(4096),   dim3(256), 0,stream, z_ws,cm,ln_st_g,ln_st_b,y);
  hipLaunchKernelGGL(k_out,   dim3(16,256), dim3(256), 0,stream, y,dwb,D_b,gate,out);
}

// Round 13
// 1664.395 us; speedup vs baseline: 1.3757x; 1.0303x over previous
//
#include <hip/hip_runtime.h>
#include <cstdint>

#define EPS 1e-5f
typedef float f32x4 __attribute__((ext_vector_type(4)));
typedef short bf8 __attribute__((ext_vector_type(8)));   // 8 bf16 vals (4 VGPRs)
typedef unsigned short u16;
typedef unsigned short u16x8 __attribute__((ext_vector_type(8)));
typedef unsigned int uint4v __attribute__((ext_vector_type(4)));

__device__ __forceinline__ u16 f2b(float f){
  unsigned x = __float_as_uint(f);
  unsigned r = x + 0x7FFFu + ((x>>16)&1u);   // round-to-nearest-even
  return (u16)(r>>16);
}
__device__ __forceinline__ float b2f(u16 h){ return __uint_as_float(((unsigned)h)<<16); }
// pack two f32 -> one dword of 2 bf16 (a in low half); round-half-up (ties differ from RNE only)
__device__ __forceinline__ unsigned pk2(float a, float b){
  unsigned ua = __float_as_uint(a) + 0x8000u;
  unsigned ub = __float_as_uint(b) + 0x8000u;
  return __builtin_amdgcn_perm(ub, ua, 0x07060302u);
}

#define GLL(gp, lp) __builtin_amdgcn_global_load_lds((__attribute__((address_space(1))) const void*)(gp), (__attribute__((address_space(3))) void*)(lp), 16, 0, 0)

// ---------------------------------------------------------------- K0: merged prep (block 0) + weight cvt (blocks 1..560)
// R16/R17: k_prep was a single block serializing the whole GPU before k_wcvt; both depend
// only on raw inputs -> one launch, prep runs alongside the weight conversion.
__global__ __launch_bounds__(1024) void k_prepw(const float* __restrict__ A, const float* __restrict__ dtp,
    const float* __restrict__ stg, const float* __restrict__ stb,
    float* __restrict__ abeta, u16* __restrict__ ft,
    const float* __restrict__ gw, const float* __restrict__ bw,
    const float* __restrict__ cw, const float* __restrict__ dw,
    u16* __restrict__ ogw, u16* __restrict__ obw, u16* __restrict__ ocw, u16* __restrict__ odw)
{
  if (blockIdx.x != 0){
    // weight cvt: 560 blocks x 1024 threads x 4 elems = 2,293,760 (exact; boundaries %4==0)
    int n = ((int)(blockIdx.x-1)*1024 + (int)threadIdx.x)*4;
    const float* src; u16* dst; int off;
    if (n < 2097152){ src=gw; dst=ogw; off=n; }
    else if (n < 2162688){ src=bw; dst=obw; off=n-2097152; }
    else if (n < 2228224){ src=cw; dst=ocw; off=n-2162688; }
    else { src=dw; dst=odw; off=n-2228224; }
    f32x4 v = *(const f32x4*)(src+off);
    uint2 pkv;
    pkv.x = (unsigned)f2b(v.x) | ((unsigned)f2b(v.y)<<16);
    pkv.y = (unsigned)f2b(v.z) | ((unsigned)f2b(v.w)<<16);
    *(uint2*)(dst+off) = pkv;
    return;
  }
  // ---- prep body (expm + Mhat hi/lo fragment table), unchanged from R15
  __shared__ float M[4096], Ta[4096], Tb[4096], P[4096];
  __shared__ float cmn[64];
  int tid = threadIdx.x;
  float dt = dtp[0];
  for (int e=tid; e<4096; e+=1024){
    float v = dt * A[e];
    int i = e>>6, j = e&63;
    M[e] = v;
    P[e] = v + (i==j ? 1.0f : 0.0f);
    Ta[e] = v;
  }
  __syncthreads();
  float* src = Ta; float* dst = Tb;
  for (int k=2;k<=14;k++){
    float inv = 1.0f/(float)k;
    int i = tid>>4, j0 = (tid&15)*4;
    float a0=0,a1=0,a2=0,a3=0;
    for (int m2=0;m2<64;m2++){
      float f = src[i*64+m2];
      const float* Mr = &M[m2*64+j0];
      a0 += f*Mr[0]; a1 += f*Mr[1]; a2 += f*Mr[2]; a3 += f*Mr[3];
    }
    a0*=inv; a1*=inv; a2*=inv; a3*=inv;
    int base=i*64+j0;
    dst[base+0]=a0; dst[base+1]=a1; dst[base+2]=a2; dst[base+3]=a3;
    P[base+0]+=a0; P[base+1]+=a1; P[base+2]+=a2; P[base+3]+=a3;
    __syncthreads();
    float* tmp=src; src=dst; dst=tmp;
  }
  if (tid<64){
    float c0=0, ab=0; int p = tid;
    for (int q2=0;q2<64;q2++){ float ap = P[q2*64+p]; c0 += stg[q2]*ap; ab += stb[q2]*ap; }
    cmn[p] = c0*(1.0f/64.0f);
    abeta[p] = ab;
  }
  __syncthreads();
  for (int e=tid; e<4096; e+=1024){
    int q2=e>>6, p=e&63;
    Ta[e] = stg[q2]*P[q2*64+p] - cmn[p];
  }
  __syncthreads();
  for (int ii=0; ii<4; ii++){
    int e = tid*4+ii;
    int j = e&7, l = (e>>3)&63, kt=(e>>9)&1, mt=e>>10;
    int q2 = 16*(2*kt + (j>>2)) + 4*(l>>4) + (j&3);
    int p = 16*mt + (l&15);
    float v = Ta[q2*64+p];
    u16 hi = f2b(v);
    float lo = v - b2f(hi);
    ft[e] = hi;
    ft[e+4096] = f2b(lo);
  }
}

// ---------------------------------------------------------------- K1: layernorm + depthwise conv + residual -> bf16
__global__ __launch_bounds__(256) void k_lnconv(const float* __restrict__ x, const float* __restrict__ gin,
  const float* __restrict__ bin, const float* __restrict__ cwt, const float* __restrict__ cb, u16* __restrict__ xn)
{
  __shared__ float red[10][8];
  int tid = threadIdx.x; int w = tid>>6; int lane = tid&63;
  int r0 = blockIdx.x*8;
  int bt = r0>>12, t0 = r0&4095;
  int c4 = tid*4;
  f32x4 g4 = *(const f32x4*)(gin + c4);
  f32x4 b4 = *(const f32x4*)(bin + c4);
  f32x4 vals[10];
  for (int lr=0; lr<10; lr++){
    int t = t0 - 1 + lr;
    f32x4 xv = {0,0,0,0};
    bool ok = (t>=0 && t<4096);
    if (ok) xv = *(const f32x4*)(x + (size_t)(bt*4096+t)*1024 + c4);
    float s = xv.x+xv.y+xv.z+xv.w;
    float q = xv.x*xv.x+xv.y*xv.y+xv.z*xv.z+xv.w*xv.w;
    for (int m2=1;m2<=32;m2<<=1){ s += __shfl_xor(s,m2,64); q += __shfl_xor(q,m2,64); }
    if (lane==0){ red[lr][w]=s; red[lr][4+w]=q; }
    __syncthreads();
    s = red[lr][0]+red[lr][1]+red[lr][2]+red[lr][3];
    q = red[lr][4]+red[lr][5]+red[lr][6]+red[lr][7];
    float mu = s*(1.f/1024.f);
    float var = q*(1.f/1024.f) - mu*mu;
    float rr = rsqrtf(var + EPS);
    f32x4 o = {0,0,0,0};
    if (ok){
      o.x=(xv.x-mu)*rr*g4.x+b4.x; o.y=(xv.y-mu)*rr*g4.y+b4.y;
      o.z=(xv.z-mu)*rr*g4.z+b4.z; o.w=(xv.w-mu)*rr*g4.w+b4.w;
    }
    vals[lr]=o;
  }
  float w0[4], w1[4], w2[4], cbv[4];
  for (int ii=0;ii<4;ii++){ int c = c4+ii; w0[ii]=cwt[c*3+0]; w1[ii]=cwt[c*3+1]; w2[ii]=cwt[c*3+2]; cbv[ii]=cb[c]; }
  for (int lr=1; lr<=8; lr++){
    int t = t0 + lr - 1;
    f32x4 o;
    o.x = vals[lr].x + w0[0]*vals[lr-1].x + w1[0]*vals[lr].x + w2[0]*vals[lr+1].x + cbv[0];
    o.y = vals[lr].y + w0[1]*vals[lr-1].y + w1[1]*vals[lr].y + w2[1]*vals[lr+1].y + cbv[1];
    o.z = vals[lr].z + w0[2]*vals[lr-1].z + w1[2]*vals[lr].z + w2[2]*vals[lr+1].z + cbv[2];
    o.w = vals[lr].w + w0[3]*vals[lr-1].w + w1[3]*vals[lr].w + w2[3]*vals[lr+1].w + cbv[3];
    size_t off = (size_t)(bt*4096+t)*1024 + c4;
    unsigned lo2 = (unsigned)f2b(o.x) | ((unsigned)f2b(o.y)<<16);
    unsigned hi2 = (unsigned)f2b(o.z) | ((unsigned)f2b(o.w)<<16);
    uint2 pk; pk.x=lo2; pk.y=hi2;
    *(uint2*)(xn + off) = pk;
  }
}

// ---------------------------------------------------------------- gate GEMM body (R6-proven; shared by k_gate_xg and k_fused)
__device__ __forceinline__ void gate_body(char* smem, int tid, int n0, int m0, bool isxg,
    const u16* __restrict__ xn, const u16* __restrict__ gw, const float* __restrict__ gb,
    u16* __restrict__ outp)
{
  u16* As = (u16*)smem;
  u16* Bs = (u16*)(smem + 8192);
  float* st = (float*)smem;
  int w=tid>>6, l=tid&63;
  int wr = w>>1, wc = w&1;
  f32x4 acc[4][4] = {};
  for (int kk=0; kk<32; kk++){
    int k0 = kk*32;
    for (int i2=0;i2<2;i2++){
      const char* ga = (const char*)xn + ((size_t)(m0+32*w+16*i2+(l>>2))*1024 + k0)*2 + (l&3)*16;
      GLL(ga, (char*)As + (32*w+16*i2)*64);
      const char* gbp = (const char*)gw + ((size_t)(n0+32*w+16*i2+(l>>2))*1024 + k0)*2 + (l&3)*16;
      GLL(gbp, (char*)Bs + (32*w+16*i2)*64);
    }
    __syncthreads();
    bf8 af[4], bfr[4];
    for (int mt=0;mt<4;mt++) af[mt] = *(const bf8*)(As + (wr*64+mt*16+(l&15))*32 + 8*(l>>4));
    for (int nt=0;nt<4;nt++) bfr[nt] = *(const bf8*)(Bs + (wc*64+nt*16+(l&15))*32 + 8*(l>>4));
    for (int mt=0;mt<4;mt++) for (int nt=0;nt<4;nt++)
      acc[mt][nt] = __builtin_amdgcn_mfma_f32_16x16x32_bf16(af[mt], bfr[nt], acc[mt][nt], 0,0,0);
    __syncthreads();
  }
  int r2 = tid>>2, q = tid&3;
  f32x4 gb4[8];
  for (int j=0;j<8;j++) gb4[j] = *(const f32x4*)(gb + n0 + q*32 + j*4);
  int g = l>>4, c = l&15;
  for (int p=0;p<2;p++){
    __syncthreads();
    if (wr==p){
      for (int mt=0;mt<4;mt++) for (int nt=0;nt<4;nt++)
        for (int r=0;r<4;r++)
          st[(mt*16+4*g+r)*132 + wc*64+nt*16+c] = acc[mt][nt][r];
    }
    __syncthreads();
    int row = m0 + p*64 + r2;
    const float* sp = st + r2*132 + q*32;
    u16 ob[32];
    if (!isxg){
      for (int j=0;j<8;j++){
        f32x4 v = *(const f32x4*)(sp + 4*j);
        v = v + gb4[j];
        ob[4*j+0] = f2b(1.0f/(1.0f+__expf(-v.x)));
        ob[4*j+1] = f2b(1.0f/(1.0f+__expf(-v.y)));
        ob[4*j+2] = f2b(1.0f/(1.0f+__expf(-v.z)));
        ob[4*j+3] = f2b(1.0f/(1.0f+__expf(-v.w)));
      }
    } else {
      const u16* xp = xn + (size_t)row*1024 + (n0-1024) + q*32;
      u16 xb[32];
      for (int j=0;j<4;j++){
        u16x8 t8 = *(const u16x8*)(xp + 8*j);
        for (int e=0;e<8;e++) xb[8*j+e] = t8[e];
      }
      for (int j=0;j<8;j++){
        f32x4 v = *(const f32x4*)(sp + 4*j);
        v = v + gb4[j];
        ob[4*j+0] = f2b(b2f(xb[4*j+0]) * (1.0f/(1.0f+__expf(-v.x))));
        ob[4*j+1] = f2b(b2f(xb[4*j+1]) * (1.0f/(1.0f+__expf(-v.y))));
        ob[4*j+2] = f2b(b2f(xb[4*j+2]) * (1.0f/(1.0f+__expf(-v.z))));
        ob[4*j+3] = f2b(b2f(xb[4*j+3]) * (1.0f/(1.0f+__expf(-v.w))));
      }
    }
    int ncol = isxg ? (n0-1024) : n0;
    u16* op = outp + (size_t)row*1024 + ncol + q*32;
    unsigned od[16];
    for (int i2=0;i2<16;i2++) od[i2] = (unsigned)ob[2*i2] | ((unsigned)ob[2*i2+1]<<16);
    uint4v s0 = {od[0],od[1],od[2],od[3]};
    uint4v s1 = {od[4],od[5],od[6],od[7]};
    uint4v s2 = {od[8],od[9],od[10],od[11]};
    uint4v s3 = {od[12],od[13],od[14],od[15]};
    *(uint4v*)(op+ 0) = s0;
    *(uint4v*)(op+ 8) = s1;
    *(uint4v*)(op+16) = s2;
    *(uint4v*)(op+24) = s3;
  }
}

// ---------------------------------------------------------------- Cm GEMM body (k_bc half==1; used by k_fused)
__device__ __forceinline__ void cm_body(char* smem, int tid, int m0,
  const u16* __restrict__ xn, const u16* __restrict__ cw, const float* __restrict__ cbias_,
  u16* __restrict__ cm)
{
  u16* As = (u16*)smem;
  u16* Bs = (u16*)(smem + 8192);
  int w=tid>>6, l=tid&63;
  f32x4 acc[2][4]={};
  for (int kk=0;kk<32;kk++){
    int k0=kk*32;
    for (int i2=0;i2<2;i2++){
      const char* ga=(const char*)xn + ((size_t)(m0+32*w+16*i2+(l>>2))*1024+k0)*2+(l&3)*16;
      GLL(ga, (char*)As+(32*w+16*i2)*64);
    }
    { const char* gbp=(const char*)cw + ((size_t)(16*w+(l>>2))*1024+k0)*2+(l&3)*16;
      GLL(gbp, (char*)Bs+(16*w)*64); }
    __syncthreads();
    bf8 af[2], bfr[4];
    for (int mt=0;mt<2;mt++) af[mt]=*(const bf8*)(As+(32*w+16*mt+(l&15))*32+8*(l>>4));
    for (int nt=0;nt<4;nt++) bfr[nt]=*(const bf8*)(Bs+(16*nt+(l&15))*32+8*(l>>4));
    for (int mt=0;mt<2;mt++) for(int nt=0;nt<4;nt++)
      acc[mt][nt]=__builtin_amdgcn_mfma_f32_16x16x32_bf16(af[mt],bfr[nt],acc[mt][nt],0,0,0);
    __syncthreads();
  }
  int g=l>>4, c=l&15;
  for (int nt=0;nt<4;nt++){ int n=16*nt+c; float bias=cbias_[n];
    for(int mt=0;mt<2;mt++) for(int r=0;r<4;r++){
      int row=m0+32*w+16*mt+4*g+r;
      cm[(size_t)row*64+n]=f2b(acc[mt][nt][r]+bias);
    }
  }
}

// ---------------------------------------------------------------- K2: xg half of gate GEMM (needed before Bm)
__global__ __launch_bounds__(256) void k_gate_xg(const u16* __restrict__ xn, const u16* __restrict__ gw,
    const float* __restrict__ gb, u16* __restrict__ xg_o)
{
  __shared__ char smem[33792];
  int flat = blockIdx.x;                        // 1024 blocks, %8==0
  int logical = (flat&7)*128 + (flat>>3);       // XCD-chunk swizzle, n fastest
  int n0 = 1024 + (logical&7)*128, m0 = (logical>>3)*128;
  gate_body(smem, threadIdx.x, n0, m0, true, xn, gw, gb, xg_o);
}

// ---------------------------------------------------------------- K3: Bm only (-> c_ws, scan layout)
__global__ __launch_bounds__(256) void k_bc_bm(const u16* __restrict__ xg, const u16* __restrict__ bw,
   const float* __restrict__ bb, const float* __restrict__ abeta, float* __restrict__ c_ws)
{
  __shared__ u16 As[128*32], Bs[64*32];
  int tid=threadIdx.x, w=tid>>6, l=tid&63;
  int m0 = blockIdx.x*128;
  f32x4 acc[2][4]={};
  for (int kk=0;kk<32;kk++){
    int k0=kk*32;
    for (int i2=0;i2<2;i2++){
      const char* ga=(const char*)xg + ((size_t)(m0+32*w+16*i2+(l>>2))*1024+k0)*2+(l&3)*16;
      GLL(ga, (char*)As+(32*w+16*i2)*64);
    }
    { const char* gbp=(const char*)bw + ((size_t)(16*w+(l>>2))*1024+k0)*2+(l&3)*16;
      GLL(gbp, (char*)Bs+(16*w)*64); }
    __syncthreads();
    bf8 af[2], bfr[4];
    for (int mt=0;mt<2;mt++) af[mt]=*(const bf8*)(As+(32*w+16*mt+(l&15))*32+8*(l>>4));
    for (int nt=0;nt<4;nt++) bfr[nt]=*(const bf8*)(Bs+(16*nt+(l&15))*32+8*(l>>4));
    for (int mt=0;mt<2;mt++) for(int nt=0;nt<4;nt++)
      acc[mt][nt]=__builtin_amdgcn_mfma_f32_16x16x32_bf16(af[mt],bfr[nt],acc[mt][nt],0,0,0);
    __syncthreads();
  }
  int g=l>>4, c=l&15;
  for (int nt=0;nt<4;nt++){ int n=16*nt+c; float bias=bb[n]; float ab=abeta[n];
    for(int mt=0;mt<2;mt++) for(int r=0;r<4;r++){
      int row=m0+32*w+16*mt+4*g+r; int bt=row>>12, t=row&4095;
      float v=acc[mt][nt][r]+bias + (t>0?ab:0.0f);
      c_ws[(size_t)t*256 + bt*64 + n] = v;
    }
  }
}

// ---------------------------------------------------------------- K4 FUSED: scan (block 0) ∥ gate-half (1..1024) ∥ Cm (1025..1152)
// R16/R17: the scan runs on ONE CU for 1326us while 255 CUs idle. The gate half (consumed
// only by k_out) and Cm (needs only xn, consumed only by k_y) are independent of the scan
// and of each other — fold them into the scan's dispatch. NO intra-kernel dependencies:
// every block's inputs were produced by earlier kernels on the stream (no flags, no
// ordering assumptions). Block 0 dispatches first; co-work (~150-250us) finishes inside
// the scan's shadow. R8 bounds interference: full-duration chip-wide spinners cost +7%;
// this co-work spans ~15% of the scan -> expect +1-3%. Scan body verbatim R15 (1326us).
__global__ __launch_bounds__(256) void k_fused(const float* __restrict__ c_ws, const u16* __restrict__ ft,
  float* __restrict__ z_ws,
  const u16* __restrict__ xn, const u16* __restrict__ gw, const float* __restrict__ gb,
  u16* __restrict__ gate_o,
  const u16* __restrict__ cw, const float* __restrict__ cbias_, u16* __restrict__ cm)
{
  __shared__ char smem[33792];
  int bid = blockIdx.x, tid = threadIdx.x;
  if (bid > 1024){
    cm_body(smem, tid, (bid-1025)*128, xn, cw, cbias_, cm);
    return;
  }
  if (bid >= 1){
    int flat = bid-1;                           // 1024 blocks, %8==0
    int logical = (flat&7)*128 + (flat>>3);
    int n0 = (logical&7)*128, m0 = (logical>>3)*128;
    gate_body(smem, tid, n0, m0, false, xn, gw, gb, gate_o);
    return;
  }
  // ---------------- block 0: scan (R15 verbatim; threads >=64 exit, no __syncthreads used)
  if (tid >= 64) return;
  float* ring = (float*)smem;      // 16 slots x 1024 B
  int l=tid, g=l>>4, b=l&3;
  const bf8* ftv=(const bf8*)ft;
  bf8 Wh[4][2], Wl[4][2];
  for(int mt=0;mt<4;mt++)for(int kt=0;kt<2;kt++){
    Wh[mt][kt]=ftv[(mt*2+kt)*64+l];
    Wl[mt][kt]=ftv[(8+mt*2+kt)*64+l];
  }
  const f32x4 zed = {0.f,0.f,0.f,0.f};
  f32x4 z0,z1,z2,z3;
  {
    const float* zp = c_ws + b*64 + 4*g;   // t=0: z_0 = c_0 (Bm omitted abeta at t==0)
    z0=*(const f32x4*)(zp+0); z1=*(const f32x4*)(zp+16); z2=*(const f32x4*)(zp+32); z3=*(const f32x4*)(zp+48);
  }
  for(int u2=1;u2<=8;u2++){
    const char* ga=(const char*)c_ws + (size_t)u2*1024 + l*16;
    GLL(ga, (char*)ring + u2*1024);
  }
  asm volatile("s_waitcnt vmcnt(0)" ::: "memory");
  unsigned laneoff;
  {
    __attribute__((address_space(3))) float* l3=( __attribute__((address_space(3))) float*)ring;
    laneoff=(unsigned)(uintptr_t)l3 + (unsigned)(b*256 + g*16);
  }
  // z store layout (fp32): z_ws[t*1024 + col*64 + 16*mt + 4*g + r], col=l&15
  unsigned voff = (unsigned)(((l&15)*64 + 4*g)*4);
  unsigned long long zb = (unsigned long long)(uintptr_t)z_ws;
  f32x4 cN0,cN1,cN2,cN3;
  bf8 zf0, zf1;

  // ---- prologue: pack zf_0 = bf16(z_0) (RAW, unnormalized); NO store (step t stores slot t)
  {
    uint4v p0,p1;
    p0.x=pk2(z0.x,z0.y); p0.y=pk2(z0.z,z0.w); p0.z=pk2(z1.x,z1.y); p0.w=pk2(z1.z,z1.w);
    p1.x=pk2(z2.x,z2.y); p1.y=pk2(z2.z,z2.w); p1.z=pk2(z3.x,z3.y); p1.w=pk2(z3.z,z3.w);
    { union { uint4v u; bf8 h; } cv; cv.u=p0; zf0=cv.h; cv.u=p1; zf1=cv.h; }
  }

  unsigned slotr = 1024u;          // ring byte offset of slot (t+1)&15
  unsigned ldst  = 9u*1024u;       // ring byte offset of slot (t+9)&15
  const char* gsrc = (const char*)c_ws + (size_t)9*1024;   // token t+9

  // per-step vm ops: 1 GLL then 4 stores. GLL for the slot read at step t was issued at
  // step t-8 with 39 newer vm-ops at this wait -> vmcnt(24) <= 39 -> safe.
  for (int t=0; t<4096; ++t){
    asm volatile("s_waitcnt vmcnt(24)" ::: "memory");
    { unsigned ro = laneoff + slotr;
      asm volatile("ds_read_b128 %0, %4 offset:0\n\t"
                   "ds_read_b128 %1, %4 offset:64\n\t"
                   "ds_read_b128 %2, %4 offset:128\n\t"
                   "ds_read_b128 %3, %4 offset:192"
                   : "=v"(cN0),"=v"(cN1),"=v"(cN2),"=v"(cN3) : "v"(ro) : "memory"); }
    GLL(gsrc + (size_t)l*16, (char*)ring + ldst);
    f32x4 u0=__builtin_amdgcn_mfma_f32_16x16x32_bf16(Wh[0][0],zf0,zed,0,0,0);
    f32x4 u1=__builtin_amdgcn_mfma_f32_16x16x32_bf16(Wh[1][0],zf0,zed,0,0,0);
    f32x4 u2=__builtin_amdgcn_mfma_f32_16x16x32_bf16(Wh[2][0],zf0,zed,0,0,0);
    f32x4 u3=__builtin_amdgcn_mfma_f32_16x16x32_bf16(Wh[3][0],zf0,zed,0,0,0);
    u0=__builtin_amdgcn_mfma_f32_16x16x32_bf16(Wh[0][1],zf1,u0,0,0,0);
    u1=__builtin_amdgcn_mfma_f32_16x16x32_bf16(Wh[1][1],zf1,u1,0,0,0);
    u2=__builtin_amdgcn_mfma_f32_16x16x32_bf16(Wh[2][1],zf1,u2,0,0,0);
    u3=__builtin_amdgcn_mfma_f32_16x16x32_bf16(Wh[3][1],zf1,u3,0,0,0);
    u0=__builtin_amdgcn_mfma_f32_16x16x32_bf16(Wl[0][0],zf0,u0,0,0,0);
    u1=__builtin_amdgcn_mfma_f32_16x16x32_bf16(Wl[1][0],zf0,u1,0,0,0);
    u2=__builtin_amdgcn_mfma_f32_16x16x32_bf16(Wl[2][0],zf0,u2,0,0,0);
    u3=__builtin_amdgcn_mfma_f32_16x16x32_bf16(Wl[3][0],zf0,u3,0,0,0);
    u0=__builtin_amdgcn_mfma_f32_16x16x32_bf16(Wl[0][1],zf1,u0,0,0,0);
    u1=__builtin_amdgcn_mfma_f32_16x16x32_bf16(Wl[1][1],zf1,u1,0,0,0);
    u2=__builtin_amdgcn_mfma_f32_16x16x32_bf16(Wl[2][1],zf1,u2,0,0,0);
    u3=__builtin_amdgcn_mfma_f32_16x16x32_bf16(Wl[3][1],zf1,u3,0,0,0);
    float rr;
    {
      f32x4 s4=(z0+z1)+(z2+z3);
      float s=(s4.x+s4.y)+(s4.z+s4.w);
      f32x4 qa=z0*z0; qa=z1*z1+qa;
      f32x4 qb=z2*z2; qb=z3*z3+qb;
      f32x4 q4=qa+qb;
      float q=(q4.x+q4.y)+(q4.z+q4.w);
      float sB=s, qB=q;
      asm("v_permlane16_swap_b32 %0, %1" : "+v"(s), "+v"(sB));
      asm("v_permlane16_swap_b32 %0, %1" : "+v"(q), "+v"(qB));
      s+=sB; q+=qB;
      float sC=s, qC=q;
      asm("v_permlane32_swap_b32 %0, %1" : "+v"(s), "+v"(sC));
      asm("v_permlane32_swap_b32 %0, %1" : "+v"(q), "+v"(qC));
      s+=sC; q+=qC;
      float mu=s*(1.f/64.f);
      float var=q*(1.f/64.f)-mu*mu;
      rr=rsqrtf(var+EPS);
    }
    asm volatile("global_store_dwordx4 %0, %1, %5\n\t"
                 "global_store_dwordx4 %0, %2, %5 offset:64\n\t"
                 "global_store_dwordx4 %0, %3, %5 offset:128\n\t"
                 "global_store_dwordx4 %0, %4, %5 offset:192"
                 :: "v"(voff), "v"(z0), "v"(z1), "v"(z2), "v"(z3), "s"(zb) : "memory");
    voff += 4096u;
    slotr = (slotr + 1024u) & 16383u;
    ldst  = (ldst  + 1024u) & 16383u;
    gsrc += 1024;
    asm volatile("s_waitcnt lgkmcnt(0)" : "+v"(cN0),"+v"(cN1),"+v"(cN2),"+v"(cN3) :: "memory");
    z0 = u0*rr + cN0;
    z1 = u1*rr + cN1;
    z2 = u2*rr + cN2;
    z3 = u3*rr + cN3;
    uint4v p0,p1;
    p0.x=pk2(z0.x,z0.y); p0.y=pk2(z0.z,z0.w); p0.z=pk2(z1.x,z1.y); p0.w=pk2(z1.z,z1.w);
    p1.x=pk2(z2.x,z2.y); p1.y=pk2(z2.z,z2.w); p1.z=pk2(z3.x,z3.y); p1.w=pk2(z3.z,z3.w);
    { union { uint4v u; bf8 h; } cv; cv.u=p0; zf0=cv.h; cv.u=p1; zf1=cv.h; }
  }
  // t=4095 stores z_4095; z_4096 never stored. GLL prefetch max token 4104 < 4112 (padding).
}

// ---------------------------------------------------------------- K4b: y_t = Cm_t * LN(z_t)
__global__ __launch_bounds__(256) void k_y(const float* __restrict__ z_ws, const u16* __restrict__ cm,
  const float* __restrict__ stg, const float* __restrict__ stb, u16* __restrict__ y)
{
  int tid=threadIdx.x, w=tid>>6, l=tid&63;
  int token = blockIdx.x*4 + w;
  int bt = token>>12, t = token&4095;
  float zv = z_ws[(size_t)t*1024 + bt*64 + l];
  float s=zv, q=zv*zv;
  for (int m2=1;m2<=32;m2<<=1){ s += __shfl_xor(s,m2,64); q += __shfl_xor(q,m2,64); }
  float mu=s*(1.f/64.f), var=q*(1.f/64.f)-mu*mu, rr=rsqrtf(var+EPS);
  float sv=(zv-mu)*rr*stg[l]+stb[l];
  y[(size_t)token*64 + l] = f2b(sv * b2f(cm[(size_t)token*64+l]));
}

// ---------------------------------------------------------------- K5: out = (y @ D_w^T + D_b) * gate
__global__ __launch_bounds__(256) void k_out(const u16* __restrict__ y, const u16* __restrict__ dw,
   const float* __restrict__ db, const u16* __restrict__ gate, float* __restrict__ out)
{
  __shared__ float tr[4][16][68];
  int tid=threadIdx.x, w=tid>>6, l=tid&63, g=l>>4, c=l&15;
  int n0=blockIdx.x*64, m0=blockIdx.y*64;
  int mrow = m0 + 16*w + c;
  bf8 af0=*(const bf8*)(y + (size_t)mrow*64 + 8*g);
  bf8 af1=*(const bf8*)(y + (size_t)mrow*64 + 32 + 8*g);
  f32x4 acc[4];
  for(int nt=0;nt<4;nt++){
    int n=n0+16*nt+c;
    bf8 b0=*(const bf8*)(dw + (size_t)n*64 + 8*g);
    bf8 b1=*(const bf8*)(dw + (size_t)n*64 + 32 + 8*g);
    f32x4 a={0,0,0,0};
    a=__builtin_amdgcn_mfma_f32_16x16x32_bf16(af0,b0,a,0,0,0);
    a=__builtin_amdgcn_mfma_f32_16x16x32_bf16(af1,b1,a,0,0,0);
    acc[nt]=a+db[n];
  }
  for(int nt=0;nt<4;nt++) for(int r=0;r<4;r++) tr[w][4*g+r][16*nt+c]=acc[nt][r];
  __syncthreads();
  int lr=l>>2, cc0=(l&3)*16;
  int grow=m0+16*w+lr;
  const u16* gp = gate + (size_t)grow*1024 + n0 + cc0;
  u16x8 g0=*(const u16x8*)(gp), g1=*(const u16x8*)(gp+8);
  float* op = out + (size_t)grow*1024 + n0 + cc0;
  float vv[16];
  for(int j2=0;j2<16;j2++){
    u16 gb16 = (j2<8)? g0[j2] : g1[j2-8];
    vv[j2]=tr[w][lr][cc0+j2]*b2f(gb16);
  }
  for(int j2=0;j2<4;j2++){
    f32x4 ov={vv[4*j2],vv[4*j2+1],vv[4*j2+2],vv[4*j2+3]};
    *(f32x4*)(op+4*j2)=ov;
  }
}

// ----------------------------------------------------------------
extern "C" void kernel_launch(void* const* d_in, const int* in_sizes, int n_in,
                              void* d_out, int out_size, void* d_ws, size_t ws_size,
                              hipStream_t stream) {
  const float* x=(const float*)d_in[0];
  const float* A=(const float*)d_in[1];
  const float* dt=(const float*)d_in[2];
  const float* B_w=(const float*)d_in[3];
  const float* B_b=(const float*)d_in[4];
  const float* C_w=(const float*)d_in[5];
  const float* C_b=(const float*)d_in[6];
  const float* D_w=(const float*)d_in[7];
  const float* D_b=(const float*)d_in[8];
  const float* conv_w=(const float*)d_in[9];
  const float* conv_b=(const float*)d_in[10];
  const float* gate_w=(const float*)d_in[11];
  const float* gate_b=(const float*)d_in[12];
  const float* ln_in_g=(const float*)d_in[13];
  const float* ln_in_b=(const float*)d_in[14];
  const float* ln_st_g=(const float*)d_in[15];
  const float* ln_st_b=(const float*)d_in[16];
  char* ws=(char*)d_ws;
  u16* xn   =(u16*)(ws);                    // 33,554,432
  u16* xg   =(u16*)(ws+33554432);           // 33,554,432
  u16* gate =(u16*)(ws+67108864);           // 33,554,432
  u16* gwb  =(u16*)(ws+100663296);          // 4,194,304
  u16* bwb  =(u16*)(ws+104857600);          // 131,072
  u16* cwb  =(u16*)(ws+104988672);          // 131,072
  u16* dwb  =(u16*)(ws+105119744);          // 131,072
  u16* cm   =(u16*)(ws+105250816);          // 2,097,152
  float* c_ws=(float*)(ws+107347968);       // 4112*1024B = 4,210,688
  float* z_ws=(float*)(ws+111558656);       // 16,777,216 (fp32 z)
  u16* y    =(u16*)(ws+128335872);          // 2,097,152
  float* abeta=(float*)(ws+130433024);      // 256
  u16* ft   =(u16*)(ws+130433280);          // 16,384
  float* out=(float*)d_out;

  hipLaunchKernelGGL(k_prepw, dim3(561),    dim3(1024),0,stream, A, dt, ln_st_g, ln_st_b, abeta, ft,
                                                            gate_w,B_w,C_w,D_w, gwb,bwb,cwb,dwb);
  hipLaunchKernelGGL(k_lnconv,dim3(2048),   dim3(256), 0,stream, x, ln_in_g, ln_in_b, conv_w, conv_b, xn);
  hipLaunchKernelGGL(k_gate_xg,dim3(1024),  dim3(256), 0,stream, xn,gwb,gate_b,xg);
  hipLaunchKernelGGL(k_bc_bm, dim3(128),    dim3(256), 0,stream, xg,bwb,B_b,abeta,c_ws);
  hipLaunchKernelGGL(k_fused, dim3(1153),   dim3(256), 0,stream, c_ws, ft, z_ws,
                                                            xn,gwb,gate_b,gate, cwb,C_b,cm);
  hipLaunchKernelGGL(k_y,     dim3(4096),   dim3(256), 0,stream, z_ws,cm,ln_st_g,ln_st_b,y);
  hipLaunchKernelGGL(k_out,   dim3(16,256), dim3(256), 0,stream, y,dwb,D_b,gate,out);
}